// Round 1
// baseline (267.834 us; speedup 1.0000x reference)
//
#include <hip/hip_runtime.h>
#include <math.h>

#define RBF_DIM 32
#define CUTOFF 5.0f
#define PI_F 3.14159265358979323846f
#define BB 16
#define PP 8000
#define NEE 80

// ws layout (element offsets; floats unless noted int)
#define CW_OFF      0                       // 8000 f32
#define GCW_OFF     8000                    // 8000*64 f32
#define AGG_OFF     (8000 + 8000*64)        // 520000: 16*80*64 f32
#define ZEJW_OFF    (AGG_OFF + BB*NEE*64)   // 601920: 101*64
#define ZEKW_OFF    (ZEJW_OFF + 101*64)     // 608384: 101*64
#define EFWB_OFF    (ZEKW_OFF + 101*64)     // 614848: 80*64
#define NORM_OFF    (EFWB_OFF + NEE*64)     // 619968: 16
#define AIDX_OFF    (NORM_OFF + 16)         // 619984: 8000 int
#define ZJA_OFF     (AIDX_OFF + 8000)       // int
#define ZKA_OFF     (ZJA_OFF + 8000)        // int
#define BOFF_OFF    (ZKA_OFF + 8000)        // 17 int

__device__ __forceinline__ float siluf(float x) { return x / (1.f + __expf(-x)); }
__device__ __forceinline__ float cutoff_fn(float r) {
    return (r < CUTOFF) ? 0.5f * (cosf(PI_F * r / CUTOFF) + 1.f) : 0.f;
}
__device__ __forceinline__ float rbff(float r, int i) {
    r = fminf(r, CUTOFF);
    float a = r * (31.0f / CUTOFF) - (float)i;
    return __expf(-0.5f * a * a);
}

// ---------------- K0: cw, deterministic compaction, batch offsets, norm, zero agg
__global__ __launch_bounds__(256) void k0_prep(
    const float* r0j, const float* r0k, const float* rjk,
    const int* pbatch, const int* pj, const int* pk, const int* zf,
    float* ws, int* wsi)
{
    __shared__ float tbs[256 * 16];
    __shared__ int sc[256];
    __shared__ int bOffL[17];
    int t = threadIdx.x;

    float* agg = ws + AGG_OFF;
    for (int i = t; i < BB * NEE * 64; i += 256) agg[i] = 0.f;
    for (int b = 0; b < 16; ++b) tbs[t * 16 + b] = 0.f;

    int cnt = 0;
    unsigned mask = 0;
    int base = t * 32;
    for (int i = 0; i < 32; ++i) {
        int p = base + i;
        if (p < PP) {
            float c = cutoff_fn(r0j[p]) * cutoff_fn(r0k[p]) * cutoff_fn(rjk[p]);
            ws[CW_OFF + p] = c;
            tbs[t * 16 + pbatch[p]] += c;
            if (c > 0.f) { cnt++; mask |= (1u << i); }
        }
    }
    sc[t] = cnt;
    __syncthreads();
    if (t < 16) {
        float s = 0.f;
        for (int i = 0; i < 256; ++i) s += tbs[i * 16 + t];
        ws[NORM_OFF + t] = s;
    }
    for (int off = 1; off < 256; off <<= 1) {
        int v = (t >= off) ? sc[t - off] : 0;
        __syncthreads();
        sc[t] += v;
        __syncthreads();
    }
    int excl = sc[t] - cnt;
    int NA = sc[255];
    int pos = excl;
    for (int i = 0; i < 32; ++i) {
        if ((mask >> i) & 1u) {
            int p = base + i;
            wsi[AIDX_OFF + pos] = p;
            wsi[ZJA_OFF + pos] = zf[pj[p]];
            wsi[ZKA_OFF + pos] = zf[pk[p]];
            pos++;
        }
    }
    if (t < 17) bOffL[t] = 0x7fffffff;
    __syncthreads();
    for (int i = t; i < NA; i += 256) {
        int b = pbatch[wsi[AIDX_OFF + i]];
        atomicMin(&bOffL[b], i);
    }
    __syncthreads();
    if (t == 0) {
        bOffL[16] = NA;
        for (int b = 15; b >= 0; --b)
            if (bOffL[b] == 0x7fffffff) bOffL[b] = bOffL[b + 1];
        for (int b = 0; b <= 16; ++b) wsi[BOFF_OFF + b] = bOffL[b];
    }
}

// ---------------- K1: pair layer-1 tables
__global__ __launch_bounds__(256) void k1_tables(
    const float* z_emb, const float* e_feat, const float* pe_w1, const float* pe_b1,
    float* ws)
{
    __shared__ float embL[4 * 32];
    int blk = blockIdx.x;
    int t = threadIdx.x;
    int r0, nrows, wbase;
    const float* src;
    float* dst;
    bool addb = false;
    if (blk < 26)      { r0 = blk * 4;        nrows = 101; src = z_emb;  wbase = 0;  dst = ws + ZEJW_OFF; }
    else if (blk < 52) { r0 = (blk - 26) * 4; nrows = 101; src = z_emb;  wbase = 32; dst = ws + ZEKW_OFF; }
    else               { r0 = (blk - 52) * 4; nrows = NEE; src = e_feat; wbase = 64; dst = ws + EFWB_OFF; addb = true; }
    if (t < 128) {
        int rl = t >> 5, i = t & 31;
        int r = r0 + rl;
        embL[t] = (r < nrows) ? src[r * 32 + i] : 0.f;
    }
    __syncthreads();
    int rl = t >> 6, c = t & 63;
    float acc = addb ? pe_b1[c] : 0.f;
    #pragma unroll
    for (int i = 0; i < 32; ++i)
        acc = fmaf(embL[rl * 32 + i], pe_w1[(wbase + i) * 64 + c], acc);
    int r = r0 + rl;
    if (r < nrows) dst[r * 64 + c] = acc;
}

// ---------------- K2: geom MLP (353->128->128->64), output gcw = g_geom * cw
__global__ __launch_bounds__(256) void k2_geom(
    const float* h_flat,
    const float* r0jG, const float* r0kG, const float* rjkG, const float* cosG,
    const int* pjG, const int* pkG,
    const float* W1, const float* b1, const float* W2, const float* b2,
    const float* W3, const float* b3,
    const float* ws, const int* wsi, float* gcw)
{
    __shared__ float inT[64][36];
    __shared__ float WL[64 * 128];   // reused as [128][64] for W3
    __shared__ float h1T[128][36];
    __shared__ float h2T[128][36];
    __shared__ int pjL[32], pkL[32];
    __shared__ float r0jL[32], r0kL[32], rjkL[32], cosL[32], cwL[32];

    int NA = wsi[BOFF_OFF + 16];
    int apBase = blockIdx.x * 32;
    if (apBase >= NA) return;
    int t = threadIdx.x;
    if (t < 32) {
        int ap = apBase + t;
        int a = wsi[AIDX_OFF + min(ap, NA - 1)];
        pjL[t] = pjG[a]; pkL[t] = pkG[a];
        r0jL[t] = r0jG[a]; r0kL[t] = r0kG[a]; rjkL[t] = rjkG[a];
        cosL[t] = cosG[a];
        cwL[t] = ws[CW_OFF + a];
    }
    __syncthreads();

    const int tc = t & 15, tr = t >> 4;
    const int c0 = tc * 8, r0 = tr * 2;
    float acc[2][8];
    #pragma unroll
    for (int j = 0; j < 2; ++j)
        #pragma unroll
        for (int q = 0; q < 8; ++q) acc[j][q] = 0.f;

    // layer 1: K = 353 padded to 384 (6 chunks of 64)
    for (int ck = 0; ck < 6; ++ck) {
        int k0 = ck * 64;
        {
            int rr = t >> 3;
            int kb = (t & 7) * 8;
            if (k0 < 256) {
                const float* hsrc = h_flat + ((k0 < 128) ? pjL[rr] : pkL[rr]) * 128
                                          + ((k0 < 128) ? k0 : (k0 - 128));
                float4 v0 = *(const float4*)(hsrc + kb);
                float4 v1 = *(const float4*)(hsrc + kb + 4);
                inT[kb + 0][rr] = v0.x; inT[kb + 1][rr] = v0.y;
                inT[kb + 2][rr] = v0.z; inT[kb + 3][rr] = v0.w;
                inT[kb + 4][rr] = v1.x; inT[kb + 5][rr] = v1.y;
                inT[kb + 6][rr] = v1.z; inT[kb + 7][rr] = v1.w;
            } else if (k0 == 256) {
                #pragma unroll
                for (int j = 0; j < 8; ++j) {
                    int kk = kb + j;
                    float r = (kk < 32) ? r0jL[rr] : r0kL[rr];
                    inT[kk][rr] = rbff(r, kk & 31);
                }
            } else {
                #pragma unroll
                for (int j = 0; j < 8; ++j) {
                    int kk = kb + j;
                    float v;
                    if (kk < 32) v = rbff(rjkL[rr], kk);
                    else if (kk == 32) v = cosL[rr];
                    else v = 0.f;
                    inT[kk][rr] = v;
                }
            }
        }
        for (int idx = t; idx < 64 * 128; idx += 256) {
            int kk = idx >> 7, c = idx & 127;
            int krow = k0 + kk;
            WL[idx] = (krow < 353) ? W1[krow * 128 + c] : 0.f;
        }
        __syncthreads();
        #pragma unroll 4
        for (int kk = 0; kk < 64; ++kk) {
            float2 in2 = *(const float2*)&inT[kk][r0];
            float4 wa = *(const float4*)&WL[kk * 128 + c0];
            float4 wb = *(const float4*)&WL[kk * 128 + c0 + 4];
            float w[8] = {wa.x, wa.y, wa.z, wa.w, wb.x, wb.y, wb.z, wb.w};
            #pragma unroll
            for (int q = 0; q < 8; ++q) {
                acc[0][q] = fmaf(in2.x, w[q], acc[0][q]);
                acc[1][q] = fmaf(in2.y, w[q], acc[1][q]);
            }
        }
        __syncthreads();
    }
    #pragma unroll
    for (int q = 0; q < 8; ++q) {
        float bb = b1[c0 + q];
        float2 v;
        v.x = siluf(acc[0][q] + bb);
        v.y = siluf(acc[1][q] + bb);
        *(float2*)&h1T[c0 + q][r0] = v;
    }
    // layer 2: K = 128 (2 chunks)
    #pragma unroll
    for (int j = 0; j < 2; ++j)
        #pragma unroll
        for (int q = 0; q < 8; ++q) acc[j][q] = 0.f;
    for (int ck = 0; ck < 2; ++ck) {
        int k0 = ck * 64;
        __syncthreads();
        for (int idx = t; idx < 64 * 128; idx += 256) {
            int kk = idx >> 7, c = idx & 127;
            WL[idx] = W2[(k0 + kk) * 128 + c];
        }
        __syncthreads();
        #pragma unroll 4
        for (int kk = 0; kk < 64; ++kk) {
            float2 in2 = *(const float2*)&h1T[k0 + kk][r0];
            float4 wa = *(const float4*)&WL[kk * 128 + c0];
            float4 wb = *(const float4*)&WL[kk * 128 + c0 + 4];
            float w[8] = {wa.x, wa.y, wa.z, wa.w, wb.x, wb.y, wb.z, wb.w};
            #pragma unroll
            for (int q = 0; q < 8; ++q) {
                acc[0][q] = fmaf(in2.x, w[q], acc[0][q]);
                acc[1][q] = fmaf(in2.y, w[q], acc[1][q]);
            }
        }
    }
    __syncthreads();   // all WL reads done
    #pragma unroll
    for (int q = 0; q < 8; ++q) {
        float bb = b2[c0 + q];
        float2 v;
        v.x = siluf(acc[0][q] + bb);
        v.y = siluf(acc[1][q] + bb);
        *(float2*)&h2T[c0 + q][r0] = v;
    }
    for (int idx = t; idx < 128 * 64; idx += 256) WL[idx] = W3[idx];
    __syncthreads();
    // layer 3: K = 128, 64 cols
    {
        int c3 = (t & 7) * 8;
        int r3 = t >> 3;
        float acc3[8];
        #pragma unroll
        for (int q = 0; q < 8; ++q) acc3[q] = 0.f;
        #pragma unroll 4
        for (int kk = 0; kk < 128; ++kk) {
            float in1 = h2T[kk][r3];
            float4 wa = *(const float4*)&WL[kk * 64 + c3];
            float4 wb = *(const float4*)&WL[kk * 64 + c3 + 4];
            float w[8] = {wa.x, wa.y, wa.z, wa.w, wb.x, wb.y, wb.z, wb.w};
            #pragma unroll
            for (int q = 0; q < 8; ++q) acc3[q] = fmaf(in1, w[q], acc3[q]);
        }
        int ap = apBase + r3;
        if (ap < NA) {
            float cwv = cwL[r3];
            float o[8];
            #pragma unroll
            for (int q = 0; q < 8; ++q) o[q] = (acc3[q] + b3[c3 + q]) * cwv;
            *(float4*)&gcw[ap * 64 + c3] = make_float4(o[0], o[1], o[2], o[3]);
            *(float4*)&gcw[ap * 64 + c3 + 4] = make_float4(o[4], o[5], o[6], o[7]);
        }
    }
}

// ---------------- K3: pair MLP layers 2-3 + contrib + aggregation
__global__ __launch_bounds__(256) void k3_pair(
    const float* ws, const int* wsi,
    const float* W2, const float* b2, const float* W3, const float* b3,
    const float* gcw, float* agg)
{
    __shared__ float hT[64][132];
    __shared__ float W2L[64 * 64];
    __shared__ float W3L[64 * 64];
    __shared__ float gcwL[32 * 64];  // reused as redBuf[8][4][64]
    __shared__ int zjL[32], zkL[32];
    __shared__ float b2L[64], b3L[64];
    __shared__ float efL[4 * 64];

    int bid = blockIdx.x;
    int b = bid & 15;
    int et = (bid >> 4) % 20;
    int ps = bid / 320;
    int e0 = et * 4;
    int t = threadIdx.x;

    int s = wsi[BOFF_OFF + b], eE = wsi[BOFF_OFF + b + 1];
    int count = eE - s;
    int half = (count + 1) >> 1;
    int myStart = s + ps * half;
    int myCount = min(half, count - ps * half);
    if (myCount < 0) myCount = 0;
    int nChunks = (myCount + 31) >> 5;

    for (int idx = t; idx < 4096; idx += 256) { W2L[idx] = W2[idx]; W3L[idx] = W3[idx]; }
    if (t < 64) { b2L[t] = b2[t]; b3L[t] = b3[t]; }
    efL[t] = ws[EFWB_OFF + e0 * 64 + t];

    const int tc = t & 7, tr = t >> 3;
    const int c0 = tc * 8, r0 = tr * 4;
    float aggAcc[8];
    #pragma unroll
    for (int q = 0; q < 8; ++q) aggAcc[q] = 0.f;

    __syncthreads();

    for (int ci = 0; ci < nChunks; ++ci) {
        int apBase = myStart + ci * 32;
        int vcnt = min(32, myStart + myCount - apBase);
        if (t < 32) {
            bool v = t < vcnt;
            zjL[t] = v ? wsi[ZJA_OFF + apBase + t] : 0;
            zkL[t] = v ? wsi[ZKA_OFF + apBase + t] : 0;
        }
        {
            int rr = t >> 3, cb = (t & 7) * 8;
            bool v = rr < vcnt;
            float4 g0 = v ? *(const float4*)&gcw[(apBase + rr) * 64 + cb]
                          : make_float4(0.f, 0.f, 0.f, 0.f);
            float4 g1 = v ? *(const float4*)&gcw[(apBase + rr) * 64 + cb + 4]
                          : make_float4(0.f, 0.f, 0.f, 0.f);
            *(float4*)&gcwL[rr * 64 + cb] = g0;
            *(float4*)&gcwL[rr * 64 + cb + 4] = g1;
        }
        __syncthreads();
        // build h1 (transposed)
        {
            int r = t & 127, chalfb = t >> 7;
            int pi = r & 31, e = r >> 5;
            const float* zjW = ws + ZEJW_OFF + zjL[pi] * 64;
            const float* zkW = ws + ZEKW_OFF + zkL[pi] * 64;
            const float* ef = efL + e * 64;
            int cb = chalfb * 32;
            #pragma unroll
            for (int q = 0; q < 8; ++q) {
                float4 a4 = *(const float4*)(zjW + cb + q * 4);
                float4 b4 = *(const float4*)(zkW + cb + q * 4);
                float4 e4 = *(const float4*)(ef + cb + q * 4);
                hT[cb + q * 4 + 0][r] = siluf(a4.x + b4.x + e4.x);
                hT[cb + q * 4 + 1][r] = siluf(a4.y + b4.y + e4.y);
                hT[cb + q * 4 + 2][r] = siluf(a4.z + b4.z + e4.z);
                hT[cb + q * 4 + 3][r] = siluf(a4.w + b4.w + e4.w);
            }
        }
        __syncthreads();
        // layer 2
        float acc[4][8];
        #pragma unroll
        for (int j = 0; j < 4; ++j)
            #pragma unroll
            for (int q = 0; q < 8; ++q) acc[j][q] = 0.f;
        #pragma unroll 4
        for (int kk = 0; kk < 64; ++kk) {
            float4 h4 = *(const float4*)&hT[kk][r0];
            float4 wa = *(const float4*)&W2L[kk * 64 + c0];
            float4 wb = *(const float4*)&W2L[kk * 64 + c0 + 4];
            float h[4] = {h4.x, h4.y, h4.z, h4.w};
            float w[8] = {wa.x, wa.y, wa.z, wa.w, wb.x, wb.y, wb.z, wb.w};
            #pragma unroll
            for (int j = 0; j < 4; ++j)
                #pragma unroll
                for (int q = 0; q < 8; ++q)
                    acc[j][q] = fmaf(h[j], w[q], acc[j][q]);
        }
        __syncthreads();
        #pragma unroll
        for (int q = 0; q < 8; ++q) {
            float bb = b2L[c0 + q];
            float4 v;
            v.x = siluf(acc[0][q] + bb);
            v.y = siluf(acc[1][q] + bb);
            v.z = siluf(acc[2][q] + bb);
            v.w = siluf(acc[3][q] + bb);
            *(float4*)&hT[c0 + q][r0] = v;
        }
        __syncthreads();
        // layer 3 + contrib
        #pragma unroll
        for (int j = 0; j < 4; ++j)
            #pragma unroll
            for (int q = 0; q < 8; ++q) acc[j][q] = 0.f;
        #pragma unroll 4
        for (int kk = 0; kk < 64; ++kk) {
            float4 h4 = *(const float4*)&hT[kk][r0];
            float4 wa = *(const float4*)&W3L[kk * 64 + c0];
            float4 wb = *(const float4*)&W3L[kk * 64 + c0 + 4];
            float h[4] = {h4.x, h4.y, h4.z, h4.w};
            float w[8] = {wa.x, wa.y, wa.z, wa.w, wb.x, wb.y, wb.z, wb.w};
            #pragma unroll
            for (int j = 0; j < 4; ++j)
                #pragma unroll
                for (int q = 0; q < 8; ++q)
                    acc[j][q] = fmaf(h[j], w[q], acc[j][q]);
        }
        int piB = r0 & 31;
        #pragma unroll
        for (int j = 0; j < 4; ++j) {
            const float* gr = &gcwL[(piB + j) * 64 + c0];
            #pragma unroll
            for (int q = 0; q < 8; ++q)
                aggAcc[q] = fmaf(acc[j][q] + b3L[c0 + q], gr[q], aggAcc[q]);
        }
        __syncthreads();
    }
    // reduction: 8 row-subgroups per (e, col)
    float* red = gcwL;
    {
        int sub = tr & 7, e = tr >> 3;
        #pragma unroll
        for (int q = 0; q < 8; ++q) red[(sub * 4 + e) * 64 + c0 + q] = aggAcc[q];
    }
    __syncthreads();
    {
        int e = t >> 6, c = t & 63;
        float s8 = 0.f;
        #pragma unroll
        for (int sub = 0; sub < 8; ++sub) s8 += red[(sub * 4 + e) * 64 + c];
        atomicAdd(&agg[(b * NEE + e0 + e) * 64 + c], s8);
    }
}

// ---------------- K4: normalize + out MLP (64->128->64)
__global__ __launch_bounds__(256) void k4_out(
    const float* ws, const float* W1, const float* b1,
    const float* W2, const float* b2, float* out)
{
    __shared__ float xT[64][68];
    __shared__ float W1L[64 * 128];
    __shared__ float hTT[128][68];
    __shared__ float W2L[128 * 64];
    __shared__ float normL[16];
    int t = threadIdx.x;
    int gbase = blockIdx.x * 64;
    if (t < 16) normL[t] = 1.f / fmaxf(ws[NORM_OFF + t], 1e-8f);
    for (int idx = t; idx < 8192; idx += 256) { W1L[idx] = W1[idx]; W2L[idx] = W2[idx]; }
    __syncthreads();
    {
        int r = t & 63, cq = t >> 6;
        int g = gbase + r;
        int b = g / NEE;
        float rn = normL[b];
        const float* arow = ws + AGG_OFF + g * 64 + cq * 16;
        #pragma unroll
        for (int q = 0; q < 4; ++q) {
            float4 v = *(const float4*)(arow + q * 4);
            int c = cq * 16 + q * 4;
            xT[c + 0][r] = v.x * rn; xT[c + 1][r] = v.y * rn;
            xT[c + 2][r] = v.z * rn; xT[c + 3][r] = v.w * rn;
        }
    }
    __syncthreads();
    {
        int tcx = t & 15, trx = t >> 4;
        int c0 = tcx * 8, r0 = trx * 4;
        float acc[4][8];
        #pragma unroll
        for (int j = 0; j < 4; ++j)
            #pragma unroll
            for (int q = 0; q < 8; ++q) acc[j][q] = 0.f;
        #pragma unroll 4
        for (int kk = 0; kk < 64; ++kk) {
            float4 x4 = *(const float4*)&xT[kk][r0];
            float4 wa = *(const float4*)&W1L[kk * 128 + c0];
            float4 wb = *(const float4*)&W1L[kk * 128 + c0 + 4];
            float x[4] = {x4.x, x4.y, x4.z, x4.w};
            float w[8] = {wa.x, wa.y, wa.z, wa.w, wb.x, wb.y, wb.z, wb.w};
            #pragma unroll
            for (int j = 0; j < 4; ++j)
                #pragma unroll
                for (int q = 0; q < 8; ++q)
                    acc[j][q] = fmaf(x[j], w[q], acc[j][q]);
        }
        #pragma unroll
        for (int q = 0; q < 8; ++q) {
            float bb = b1[c0 + q];
            float4 v;
            v.x = siluf(acc[0][q] + bb);
            v.y = siluf(acc[1][q] + bb);
            v.z = siluf(acc[2][q] + bb);
            v.w = siluf(acc[3][q] + bb);
            *(float4*)&hTT[c0 + q][r0] = v;
        }
    }
    __syncthreads();
    {
        int tcx = t & 7, trx = t >> 3;
        int c0 = tcx * 8, r0 = trx * 2;
        float acc[2][8];
        #pragma unroll
        for (int j = 0; j < 2; ++j)
            #pragma unroll
            for (int q = 0; q < 8; ++q) acc[j][q] = 0.f;
        #pragma unroll 4
        for (int kk = 0; kk < 128; ++kk) {
            float2 x2 = *(const float2*)&hTT[kk][r0];
            float4 wa = *(const float4*)&W2L[kk * 64 + c0];
            float4 wb = *(const float4*)&W2L[kk * 64 + c0 + 4];
            float w[8] = {wa.x, wa.y, wa.z, wa.w, wb.x, wb.y, wb.z, wb.w};
            #pragma unroll
            for (int q = 0; q < 8; ++q) {
                acc[0][q] = fmaf(x2.x, w[q], acc[0][q]);
                acc[1][q] = fmaf(x2.y, w[q], acc[1][q]);
            }
        }
        int g = gbase + r0;
        #pragma unroll
        for (int j = 0; j < 2; ++j) {
            float o[8];
            #pragma unroll
            for (int q = 0; q < 8; ++q) o[q] = acc[j][q] + b2[c0 + q];
            *(float4*)&out[(g + j) * 64 + c0] = make_float4(o[0], o[1], o[2], o[3]);
            *(float4*)&out[(g + j) * 64 + c0 + 4] = make_float4(o[4], o[5], o[6], o[7]);
        }
    }
}

extern "C" void kernel_launch(void* const* d_in, const int* in_sizes, int n_in,
                              void* d_out, int out_size, void* d_ws, size_t ws_size,
                              hipStream_t stream) {
    (void)in_sizes; (void)n_in; (void)out_size; (void)ws_size;
    const float* h_flat = (const float*)d_in[0];
    const int*   z_flat = (const int*)d_in[1];
    const float* e_feat = (const float*)d_in[2];
    const int*   path_j = (const int*)d_in[3];
    const int*   path_k = (const int*)d_in[4];
    const float* r0j    = (const float*)d_in[5];
    const float* r0k    = (const float*)d_in[6];
    const float* rjk    = (const float*)d_in[7];
    const float* cosang = (const float*)d_in[8];
    const int*   pbatch = (const int*)d_in[9];
    const float* z_emb  = (const float*)d_in[11];
    const float* pe_w1  = (const float*)d_in[12];
    const float* pe_b1  = (const float*)d_in[13];
    const float* pe_w2  = (const float*)d_in[14];
    const float* pe_b2  = (const float*)d_in[15];
    const float* pe_w3  = (const float*)d_in[16];
    const float* pe_b3  = (const float*)d_in[17];
    const float* gm_w1  = (const float*)d_in[18];
    const float* gm_b1  = (const float*)d_in[19];
    const float* gm_w2  = (const float*)d_in[20];
    const float* gm_b2  = (const float*)d_in[21];
    const float* gm_w3  = (const float*)d_in[22];
    const float* gm_b3  = (const float*)d_in[23];
    const float* op_w1  = (const float*)d_in[24];
    const float* op_b1  = (const float*)d_in[25];
    const float* op_w2  = (const float*)d_in[26];
    const float* op_b2  = (const float*)d_in[27];

    float* ws  = (float*)d_ws;
    int*   wsi = (int*)d_ws;
    float* gcw = ws + GCW_OFF;
    float* agg = ws + AGG_OFF;

    hipLaunchKernelGGL(k0_prep, dim3(1), dim3(256), 0, stream,
                       r0j, r0k, rjk, pbatch, path_j, path_k, z_flat, ws, wsi);
    hipLaunchKernelGGL(k1_tables, dim3(72), dim3(256), 0, stream,
                       z_emb, e_feat, pe_w1, pe_b1, ws);
    hipLaunchKernelGGL(k2_geom, dim3(250), dim3(256), 0, stream,
                       h_flat, r0j, r0k, rjk, cosang, path_j, path_k,
                       gm_w1, gm_b1, gm_w2, gm_b2, gm_w3, gm_b3, ws, wsi, gcw);
    hipLaunchKernelGGL(k3_pair, dim3(640), dim3(256), 0, stream,
                       ws, wsi, pe_w2, pe_b2, pe_w3, pe_b3, gcw, agg);
    hipLaunchKernelGGL(k4_out, dim3(20), dim3(256), 0, stream,
                       ws, op_w1, op_b1, op_w2, op_b2, (float*)d_out);
}

// Round 2
// 224.230 us; speedup vs baseline: 1.1945x; 1.1945x over previous
//
#include <hip/hip_runtime.h>
#include <math.h>

typedef float f32x4 __attribute__((ext_vector_type(4)));
typedef short bf16x8 __attribute__((ext_vector_type(8)));
typedef unsigned short u16;

#define RBF_DIM 32
#define CUTOFF 5.0f
#define PI_F 3.14159265358979323846f
#define BB 16
#define PP 8000
#define NEE 80

// ws layout (f32-element offsets)
#define CW_OFF      0            // 8000
#define GCW_OFF     8000         // 8000*64
#define AGG_OFF     520000       // 16*80*64 = 81920
#define ZEJW_OFF    601920       // 101*64
#define ZEKW_OFF    608384       // 101*64
#define EFWB_OFF    614848       // 80*64
#define NORM_OFF    619968       // 16
#define AIDX_OFF    619984       // 8000 int
#define ZJA_OFF     627984       // 8000 int
#define ZKA_OFF     635984       // 8000 int
#define BOFF_OFF    643984       // 17 int (batch starts in compacted array + NA)
#define BCNT_OFF    644004       // 32 int
#define BSUM_OFF    644036       // 512 f32
#define BCNTB_OFF   644548       // 512 int
#define BLKOFF_OFF  645060       // 33 int
#define CHS_OFF     645096       // 266 int chunk start
#define CHC_OFF     645362       // 266 int chunk count
#define CHB_OFF     645628       // 266 int chunk batch
#define NC_OFF      645894       // 1 int
#define W2THI_OFF   645896       // 2048 f32 = 4096 u16 (W2^T hi bf16)
#define W2TLO_OFF   647944
#define W3THI_OFF   649992
#define W3TLO_OFF   652040
// end 654088 f32 (~2.62 MB)

__device__ __forceinline__ float siluf(float x) { return x / (1.f + __expf(-x)); }
__device__ __forceinline__ float cutoff_fn(float r) {
    return (r < CUTOFF) ? 0.5f * (cosf(PI_F * r / CUTOFF) + 1.f) : 0.f;
}
__device__ __forceinline__ float rbff(float r, int i) {
    r = fminf(r, CUTOFF);
    float a = r * (31.0f / CUTOFF) - (float)i;
    return __expf(-0.5f * a * a);
}
__device__ __forceinline__ u16 f2bf_rne(float x) {
    unsigned u = __float_as_uint(x);
    return (u16)((u + 0x7FFFu + ((u >> 16) & 1u)) >> 16);
}
__device__ __forceinline__ void splitpack8(const float* xs, bf16x8& hi, bf16x8& lo) {
    #pragma unroll
    for (int i = 0; i < 8; ++i) {
        u16 h = f2bf_rne(xs[i]);
        float hf = __uint_as_float(((unsigned)h) << 16);
        hi[i] = (short)h;
        lo[i] = (short)f2bf_rne(xs[i] - hf);
    }
}

// ---------------- K0a: cw, agg zero, per-block counts + per-batch sums (deterministic)
__global__ __launch_bounds__(256) void k0a(
    const float* r0j, const float* r0k, const float* rjk, const int* pbatch,
    float* ws, int* wsi)
{
    __shared__ float cwL[256];
    __shared__ int bL[256];
    __shared__ int redC[256];
    int bi = blockIdx.x, t = threadIdx.x;
    for (int i = t; i < 2560; i += 256) ws[AGG_OFF + bi*2560 + i] = 0.f;
    int p = bi*250 + t;
    float cw = 0.f; int bin = -1; int valid = 0;
    if (t < 250) {
        cw = cutoff_fn(r0j[p]) * cutoff_fn(r0k[p]) * cutoff_fn(rjk[p]);
        ws[CW_OFF + p] = cw;
        bin = pbatch[p];
        valid = (cw > 0.f) ? 1 : 0;
    }
    cwL[t] = cw; bL[t] = bin; redC[t] = valid;
    __syncthreads();
    if (t < 16) {
        float s = 0.f; int c2 = 0;
        for (int i = 0; i < 256; ++i) {
            bool m = (bL[i] == t);
            s += m ? cwL[i] : 0.f;
            c2 += (m && cwL[i] > 0.f) ? 1 : 0;
        }
        ws[BSUM_OFF + bi*16 + t] = s;
        wsi[BCNTB_OFF + bi*16 + t] = c2;
    }
    __syncthreads();
    for (int s = 128; s > 0; s >>= 1) {
        if (t < s) redC[t] += redC[t + s];
        __syncthreads();
    }
    if (t == 0) wsi[BCNT_OFF + bi] = redC[0];
}

// ---------------- K0b: scans, norm, chunk table (1 block)
__global__ __launch_bounds__(64) void k0b(float* ws, int* wsi)
{
    int t = threadIdx.x;
    if (t < 16) {
        float s = 0.f;
        for (int bi = 0; bi < 32; ++bi) s += ws[BSUM_OFF + bi*16 + t];
        ws[NORM_OFF + t] = s;
    }
    if (t == 0) {
        int off = 0;
        for (int bi = 0; bi < 32; ++bi) { wsi[BLKOFF_OFF + bi] = off; off += wsi[BCNT_OFF + bi]; }
        wsi[BLKOFF_OFF + 32] = off;
        int bs = 0;
        for (int b = 0; b < 16; ++b) {
            wsi[BOFF_OFF + b] = bs;
            int cb = 0;
            for (int bi = 0; bi < 32; ++bi) cb += wsi[BCNTB_OFF + bi*16 + b];
            bs += cb;
        }
        wsi[BOFF_OFF + 16] = bs;   // NA
        int nc = 0;
        for (int b = 0; b < 16; ++b) {
            int s0 = wsi[BOFF_OFF + b], e0 = wsi[BOFF_OFF + b + 1];
            for (int x = s0; x < e0; x += 32) {
                wsi[CHS_OFF + nc] = x;
                wsi[CHC_OFF + nc] = (e0 - x < 32) ? (e0 - x) : 32;
                wsi[CHB_OFF + nc] = b;
                nc++;
            }
        }
        wsi[NC_OFF] = nc;
    }
}

// ---------------- K0c: deterministic compaction
__global__ __launch_bounds__(256) void k0c(
    const int* pj, const int* pk, const int* zf, const float* ws, int* wsi)
{
    __shared__ int sc[256];
    int bi = blockIdx.x, t = threadIdx.x;
    int p = bi*250 + t;
    int valid = (t < 250 && ws[CW_OFF + p] > 0.f) ? 1 : 0;
    sc[t] = valid;
    __syncthreads();
    for (int off = 1; off < 256; off <<= 1) {
        int v = (t >= off) ? sc[t - off] : 0;
        __syncthreads();
        sc[t] += v;
        __syncthreads();
    }
    if (valid) {
        int pos = wsi[BLKOFF_OFF + bi] + sc[t] - 1;
        wsi[AIDX_OFF + pos] = p;
        wsi[ZJA_OFF + pos] = zf[pj[p]];
        wsi[ZKA_OFF + pos] = zf[pk[p]];
    }
}

// ---------------- K1: pair layer-1 tables + W2^T/W3^T bf16 hi/lo planes
__global__ __launch_bounds__(256) void k1_tables(
    const float* z_emb, const float* e_feat, const float* pe_w1, const float* pe_b1,
    const float* pe_w2, const float* pe_w3, float* ws)
{
    int blk = blockIdx.x;
    int t = threadIdx.x;
    if (blk >= 72) {
        const float* W = (blk == 72) ? pe_w2 : pe_w3;
        u16* hiD = (u16*)(ws + ((blk == 72) ? W2THI_OFF : W3THI_OFF));
        u16* loD = (u16*)(ws + ((blk == 72) ? W2TLO_OFF : W3TLO_OFF));
        for (int idx = t; idx < 4096; idx += 256) {
            int k = idx >> 6, n = idx & 63;
            float v = W[idx];
            u16 h = f2bf_rne(v);
            float hf = __uint_as_float(((unsigned)h) << 16);
            hiD[n*64 + k] = h;
            loD[n*64 + k] = f2bf_rne(v - hf);
        }
        return;
    }
    __shared__ float embL[4 * 32];
    int r0, nrows, wbase;
    const float* src;
    float* dst;
    bool addb = false;
    if (blk < 26)      { r0 = blk * 4;        nrows = 101; src = z_emb;  wbase = 0;  dst = ws + ZEJW_OFF; }
    else if (blk < 52) { r0 = (blk - 26) * 4; nrows = 101; src = z_emb;  wbase = 32; dst = ws + ZEKW_OFF; }
    else               { r0 = (blk - 52) * 4; nrows = NEE; src = e_feat; wbase = 64; dst = ws + EFWB_OFF; addb = true; }
    if (t < 128) {
        int rl = t >> 5, i = t & 31;
        int r = r0 + rl;
        embL[t] = (r < nrows) ? src[r * 32 + i] : 0.f;
    }
    __syncthreads();
    int rl = t >> 6, c = t & 63;
    float acc = addb ? pe_b1[c] : 0.f;
    #pragma unroll
    for (int i = 0; i < 32; ++i)
        acc = fmaf(embL[rl * 32 + i], pe_w1[(wbase + i) * 64 + c], acc);
    int r = r0 + rl;
    if (r < nrows) dst[r * 64 + c] = acc;
}

// ---------------- K2: geom MLP (353->128->128->64), output gcw = g_geom * cw
__global__ __launch_bounds__(256) void k2_geom(
    const float* h_flat,
    const float* r0jG, const float* r0kG, const float* rjkG, const float* cosG,
    const int* pjG, const int* pkG,
    const float* W1, const float* b1, const float* W2, const float* b2,
    const float* W3, const float* b3,
    const float* ws, const int* wsi, float* gcw)
{
    __shared__ float inT[64][36];
    __shared__ float WL[64 * 128];
    __shared__ float h1T[128][36];
    __shared__ float h2T[128][36];
    __shared__ int pjL[32], pkL[32];
    __shared__ float r0jL[32], r0kL[32], rjkL[32], cosL[32], cwL[32];

    int NA = wsi[BOFF_OFF + 16];
    int apBase = blockIdx.x * 32;
    if (apBase >= NA) return;
    int t = threadIdx.x;
    if (t < 32) {
        int ap = apBase + t;
        int a = wsi[AIDX_OFF + min(ap, NA - 1)];
        pjL[t] = pjG[a]; pkL[t] = pkG[a];
        r0jL[t] = r0jG[a]; r0kL[t] = r0kG[a]; rjkL[t] = rjkG[a];
        cosL[t] = cosG[a];
        cwL[t] = ws[CW_OFF + a];
    }
    __syncthreads();

    const int tc = t & 15, tr = t >> 4;
    const int c0 = tc * 8, r0 = tr * 2;
    float acc[2][8];
    #pragma unroll
    for (int j = 0; j < 2; ++j)
        #pragma unroll
        for (int q = 0; q < 8; ++q) acc[j][q] = 0.f;

    for (int ck = 0; ck < 6; ++ck) {
        int k0 = ck * 64;
        {
            int rr = t >> 3;
            int kb = (t & 7) * 8;
            if (k0 < 256) {
                const float* hsrc = h_flat + ((k0 < 128) ? pjL[rr] : pkL[rr]) * 128
                                          + ((k0 < 128) ? k0 : (k0 - 128));
                float4 v0 = *(const float4*)(hsrc + kb);
                float4 v1 = *(const float4*)(hsrc + kb + 4);
                inT[kb + 0][rr] = v0.x; inT[kb + 1][rr] = v0.y;
                inT[kb + 2][rr] = v0.z; inT[kb + 3][rr] = v0.w;
                inT[kb + 4][rr] = v1.x; inT[kb + 5][rr] = v1.y;
                inT[kb + 6][rr] = v1.z; inT[kb + 7][rr] = v1.w;
            } else if (k0 == 256) {
                #pragma unroll
                for (int j = 0; j < 8; ++j) {
                    int kk = kb + j;
                    float r = (kk < 32) ? r0jL[rr] : r0kL[rr];
                    inT[kk][rr] = rbff(r, kk & 31);
                }
            } else {
                #pragma unroll
                for (int j = 0; j < 8; ++j) {
                    int kk = kb + j;
                    float v;
                    if (kk < 32) v = rbff(rjkL[rr], kk);
                    else if (kk == 32) v = cosL[rr];
                    else v = 0.f;
                    inT[kk][rr] = v;
                }
            }
        }
        for (int idx = t; idx < 64 * 128; idx += 256) {
            int kk = idx >> 7, c = idx & 127;
            int krow = k0 + kk;
            WL[idx] = (krow < 353) ? W1[krow * 128 + c] : 0.f;
        }
        __syncthreads();
        #pragma unroll 4
        for (int kk = 0; kk < 64; ++kk) {
            float2 in2 = *(const float2*)&inT[kk][r0];
            float4 wa = *(const float4*)&WL[kk * 128 + c0];
            float4 wb = *(const float4*)&WL[kk * 128 + c0 + 4];
            float w[8] = {wa.x, wa.y, wa.z, wa.w, wb.x, wb.y, wb.z, wb.w};
            #pragma unroll
            for (int q = 0; q < 8; ++q) {
                acc[0][q] = fmaf(in2.x, w[q], acc[0][q]);
                acc[1][q] = fmaf(in2.y, w[q], acc[1][q]);
            }
        }
        __syncthreads();
    }
    #pragma unroll
    for (int q = 0; q < 8; ++q) {
        float bb = b1[c0 + q];
        float2 v;
        v.x = siluf(acc[0][q] + bb);
        v.y = siluf(acc[1][q] + bb);
        *(float2*)&h1T[c0 + q][r0] = v;
    }
    #pragma unroll
    for (int j = 0; j < 2; ++j)
        #pragma unroll
        for (int q = 0; q < 8; ++q) acc[j][q] = 0.f;
    for (int ck = 0; ck < 2; ++ck) {
        int k0 = ck * 64;
        __syncthreads();
        for (int idx = t; idx < 64 * 128; idx += 256) {
            int kk = idx >> 7, c = idx & 127;
            WL[idx] = W2[(k0 + kk) * 128 + c];
        }
        __syncthreads();
        #pragma unroll 4
        for (int kk = 0; kk < 64; ++kk) {
            float2 in2 = *(const float2*)&h1T[k0 + kk][r0];
            float4 wa = *(const float4*)&WL[kk * 128 + c0];
            float4 wb = *(const float4*)&WL[kk * 128 + c0 + 4];
            float w[8] = {wa.x, wa.y, wa.z, wa.w, wb.x, wb.y, wb.z, wb.w};
            #pragma unroll
            for (int q = 0; q < 8; ++q) {
                acc[0][q] = fmaf(in2.x, w[q], acc[0][q]);
                acc[1][q] = fmaf(in2.y, w[q], acc[1][q]);
            }
        }
    }
    __syncthreads();
    #pragma unroll
    for (int q = 0; q < 8; ++q) {
        float bb = b2[c0 + q];
        float2 v;
        v.x = siluf(acc[0][q] + bb);
        v.y = siluf(acc[1][q] + bb);
        *(float2*)&h2T[c0 + q][r0] = v;
    }
    for (int idx = t; idx < 128 * 64; idx += 256) WL[idx] = W3[idx];
    __syncthreads();
    {
        int c3 = (t & 7) * 8;
        int r3 = t >> 3;
        float acc3[8];
        #pragma unroll
        for (int q = 0; q < 8; ++q) acc3[q] = 0.f;
        #pragma unroll 4
        for (int kk = 0; kk < 128; ++kk) {
            float in1 = h2T[kk][r3];
            float4 wa = *(const float4*)&WL[kk * 64 + c3];
            float4 wb = *(const float4*)&WL[kk * 64 + c3 + 4];
            float w[8] = {wa.x, wa.y, wa.z, wa.w, wb.x, wb.y, wb.z, wb.w};
            #pragma unroll
            for (int q = 0; q < 8; ++q) acc3[q] = fmaf(in1, w[q], acc3[q]);
        }
        int ap = apBase + r3;
        if (ap < NA) {
            float cwv = cwL[r3];
            float o[8];
            #pragma unroll
            for (int q = 0; q < 8; ++q) o[q] = (acc3[q] + b3[c3 + q]) * cwv;
            *(float4*)&gcw[ap * 64 + c3] = make_float4(o[0], o[1], o[2], o[3]);
            *(float4*)&gcw[ap * 64 + c3 + 4] = make_float4(o[4], o[5], o[6], o[7]);
        }
    }
}

// ---------------- K3: pair MLP layers 2-3 via MFMA bf16 hi/lo + contrib + aggregation
// Block = 1 chunk (<=32 paths) x 8 e-values. 4 waves, wave w handles e = et*8 + 2w + {0,1}.
// Transposed matmul: h2^T = W2^T(A) @ h1^T(B); out3^T = W3^T(A) @ h2^T(B).
// Fragments: A[row=lane&15][k=(lane>>4)*8+i], B[k=(lane>>4)*8+i][col=lane&15],
//            D[row=(lane>>4)*4+r][col=lane&15].
__global__ __launch_bounds__(256) void k3_pair_mfma(
    const float* ws, const int* wsi, const float* gcw, float* agg,
    const float* b2g, const float* b3g)
{
    __shared__ __align__(16) float sL[32 * 64];       // zjW+zkW sums, XOR-swizzled
    __shared__ __align__(16) u16 h2h[4][2048];        // per-wave h2 hi plane (32p x 64f)
    __shared__ __align__(16) u16 h2l[4][2048];        // per-wave h2 lo plane

    int NC = wsi[NC_OFF];
    int bid = blockIdx.x;
    int cid = bid / 10;
    int et  = bid - cid * 10;
    if (cid >= NC) return;
    int cs  = wsi[CHS_OFF + cid];
    int cnt = wsi[CHC_OFF + cid];
    int bb  = wsi[CHB_OFF + cid];

    int t = threadIdx.x;
    int lane = t & 63, w = t >> 6;
    int c = lane & 15, g = lane >> 4;

    // build sL: thread -> path p=t>>3, k-chunk (t&7)*8
    {
        int p = t >> 3, kc = (t & 7) * 8;
        int ap = cs + min(p, cnt - 1);
        int zj = wsi[ZJA_OFF + ap], zk = wsi[ZKA_OFF + ap];
        const f32x4* rj = (const f32x4*)(ws + ZEJW_OFF + zj * 64 + kc);
        const f32x4* rk = (const f32x4*)(ws + ZEKW_OFF + zk * 64 + kc);
        f32x4 s0 = rj[0] + rk[0];
        f32x4 s1 = rj[1] + rk[1];
        int sw = (p & 7) << 2;
        *(f32x4*)(sL + ((p * 64 + kc) ^ sw))     = s0;
        *(f32x4*)(sL + ((p * 64 + kc + 4) ^ sw)) = s1;
    }

    // W fragments (resident), biases
    const u16* w2hi = (const u16*)(ws + W2THI_OFF);
    const u16* w2lo = (const u16*)(ws + W2TLO_OFF);
    const u16* w3hi = (const u16*)(ws + W3THI_OFF);
    const u16* w3lo = (const u16*)(ws + W3TLO_OFF);
    bf16x8 A2h[4][2], A2l[4][2], A3h[4][2], A3l[4][2];
    #pragma unroll
    for (int mt = 0; mt < 4; ++mt)
        #pragma unroll
        for (int ks = 0; ks < 2; ++ks) {
            int off = (mt * 16 + c) * 64 + ks * 32 + g * 8;
            A2h[mt][ks] = *(const bf16x8*)(w2hi + off);
            A2l[mt][ks] = *(const bf16x8*)(w2lo + off);
            A3h[mt][ks] = *(const bf16x8*)(w3hi + off);
            A3l[mt][ks] = *(const bf16x8*)(w3lo + off);
        }
    f32x4 b2f[4], b3f[4];
    #pragma unroll
    for (int mt = 0; mt < 4; ++mt) {
        b2f[mt] = *(const f32x4*)(b2g + mt * 16 + 4 * g);
        b3f[mt] = *(const f32x4*)(b3g + mt * 16 + 4 * g);
    }
    __syncthreads();   // sL ready

    u16* myh = h2h[w];
    u16* myl = h2l[w];
    const float* efp = ws + EFWB_OFF;

    #pragma unroll 1
    for (int ei = 0; ei < 2; ++ei) {
        int e = et * 8 + w * 2 + ei;
        // h1 B-fragments: h1 = silu(sL + ef[e])
        bf16x8 Bh[2][2], Bl[2][2];
        #pragma unroll
        for (int ks = 0; ks < 2; ++ks) {
            f32x4 e0 = *(const f32x4*)(efp + e * 64 + ks * 32 + g * 8);
            f32x4 e1 = *(const f32x4*)(efp + e * 64 + ks * 32 + g * 8 + 4);
            #pragma unroll
            for (int nt = 0; nt < 2; ++nt) {
                int p = nt * 16 + c;
                int sw = (p & 7) << 2;
                int base = p * 64 + ks * 32 + g * 8;
                f32x4 x0 = *(const f32x4*)(sL + (base ^ sw));
                f32x4 x1 = *(const f32x4*)(sL + ((base + 4) ^ sw));
                x0 += e0; x1 += e1;
                float xs[8];
                #pragma unroll
                for (int i = 0; i < 4; ++i) { xs[i] = siluf(x0[i]); xs[4 + i] = siluf(x1[i]); }
                splitpack8(xs, Bh[nt][ks], Bl[nt][ks]);
            }
        }
        // layer 2 MFMA
        f32x4 acc[4][2];
        #pragma unroll
        for (int mt = 0; mt < 4; ++mt)
            #pragma unroll
            for (int nt = 0; nt < 2; ++nt) {
                f32x4 d = {0.f, 0.f, 0.f, 0.f};
                #pragma unroll
                for (int ks = 0; ks < 2; ++ks) {
                    d = __builtin_amdgcn_mfma_f32_16x16x32_bf16(A2h[mt][ks], Bh[nt][ks], d, 0, 0, 0);
                    d = __builtin_amdgcn_mfma_f32_16x16x32_bf16(A2h[mt][ks], Bl[nt][ks], d, 0, 0, 0);
                    d = __builtin_amdgcn_mfma_f32_16x16x32_bf16(A2l[mt][ks], Bh[nt][ks], d, 0, 0, 0);
                }
                acc[mt][nt] = d;
            }
        // h2 = silu(acc + b2) -> per-wave LDS planes (bf16 hi/lo), XOR-swizzled
        #pragma unroll
        for (int mt = 0; mt < 4; ++mt)
            #pragma unroll
            for (int nt = 0; nt < 2; ++nt) {
                f32x4 h = acc[mt][nt] + b2f[mt];
                u16 hs[4], ls[4];
                #pragma unroll
                for (int r = 0; r < 4; ++r) {
                    float v = siluf(h[r]);
                    u16 hh = f2bf_rne(v);
                    float hf = __uint_as_float(((unsigned)hh) << 16);
                    hs[r] = hh;
                    ls[r] = f2bf_rne(v - hf);
                }
                int p = nt * 16 + c;
                int idx = (p * 64 + mt * 16 + 4 * g) ^ ((p & 7) << 3);
                uint2 uh, ul;
                uh.x = (unsigned)hs[0] | ((unsigned)hs[1] << 16);
                uh.y = (unsigned)hs[2] | ((unsigned)hs[3] << 16);
                ul.x = (unsigned)ls[0] | ((unsigned)ls[1] << 16);
                ul.y = (unsigned)ls[2] | ((unsigned)ls[3] << 16);
                *(uint2*)(myh + idx) = uh;
                *(uint2*)(myl + idx) = ul;
            }
        // layer 3 B-fragments from LDS (same-wave dep; compiler inserts lgkmcnt)
        bf16x8 Ch[2][2], Cl[2][2];
        #pragma unroll
        for (int nt = 0; nt < 2; ++nt)
            #pragma unroll
            for (int ks = 0; ks < 2; ++ks) {
                int p = nt * 16 + c;
                int idx = (p * 64 + ks * 32 + g * 8) ^ ((p & 7) << 3);
                Ch[nt][ks] = *(const bf16x8*)(myh + idx);
                Cl[nt][ks] = *(const bf16x8*)(myl + idx);
            }
        // layer 3 MFMA
        #pragma unroll
        for (int mt = 0; mt < 4; ++mt)
            #pragma unroll
            for (int nt = 0; nt < 2; ++nt) {
                f32x4 d = {0.f, 0.f, 0.f, 0.f};
                #pragma unroll
                for (int ks = 0; ks < 2; ++ks) {
                    d = __builtin_amdgcn_mfma_f32_16x16x32_bf16(A3h[mt][ks], Ch[nt][ks], d, 0, 0, 0);
                    d = __builtin_amdgcn_mfma_f32_16x16x32_bf16(A3h[mt][ks], Cl[nt][ks], d, 0, 0, 0);
                    d = __builtin_amdgcn_mfma_f32_16x16x32_bf16(A3l[mt][ks], Ch[nt][ks], d, 0, 0, 0);
                }
                acc[mt][nt] = d;
            }
        // epilogue: contrib = (out3 + b3) * gcw, reduce over paths, atomic into agg
        float part[16];
        #pragma unroll
        for (int i = 0; i < 16; ++i) part[i] = 0.f;
        #pragma unroll
        for (int mt = 0; mt < 4; ++mt)
            #pragma unroll
            for (int nt = 0; nt < 2; ++nt) {
                f32x4 o = acc[mt][nt] + b3f[mt];
                int pl = nt * 16 + c;
                f32x4 gv = {0.f, 0.f, 0.f, 0.f};
                if (pl < cnt) gv = *(const f32x4*)(gcw + (cs + pl) * 64 + mt * 16 + 4 * g);
                #pragma unroll
                for (int r = 0; r < 4; ++r) part[mt * 4 + r] += o[r] * gv[r];
            }
        #pragma unroll
        for (int i = 0; i < 16; ++i) {
            float v = part[i];
            v += __shfl_xor(v, 1, 64);
            v += __shfl_xor(v, 2, 64);
            v += __shfl_xor(v, 4, 64);
            v += __shfl_xor(v, 8, 64);
            part[i] = v;
        }
        if (c == 0) {
            float* arow = agg + (bb * NEE + e) * 64;
            #pragma unroll
            for (int mt = 0; mt < 4; ++mt)
                #pragma unroll
                for (int r = 0; r < 4; ++r)
                    atomicAdd(arow + mt * 16 + 4 * g + r, part[mt * 4 + r]);
        }
    }
}

// ---------------- K4: normalize + out MLP (64->128->64)
__global__ __launch_bounds__(256) void k4_out(
    const float* ws, const float* W1, const float* b1,
    const float* W2, const float* b2, float* out)
{
    __shared__ float xT[64][68];
    __shared__ float W1L[64 * 128];
    __shared__ float hTT[128][68];
    __shared__ float W2L[128 * 64];
    __shared__ float normL[16];
    int t = threadIdx.x;
    int gbase = blockIdx.x * 64;
    if (t < 16) normL[t] = 1.f / fmaxf(ws[NORM_OFF + t], 1e-8f);
    for (int idx = t; idx < 8192; idx += 256) { W1L[idx] = W1[idx]; W2L[idx] = W2[idx]; }
    __syncthreads();
    {
        int r = t & 63, cq = t >> 6;
        int gg = gbase + r;
        int b = gg / NEE;
        float rn = normL[b];
        const float* arow = ws + AGG_OFF + gg * 64 + cq * 16;
        #pragma unroll
        for (int q = 0; q < 4; ++q) {
            float4 v = *(const float4*)(arow + q * 4);
            int c = cq * 16 + q * 4;
            xT[c + 0][r] = v.x * rn; xT[c + 1][r] = v.y * rn;
            xT[c + 2][r] = v.z * rn; xT[c + 3][r] = v.w * rn;
        }
    }
    __syncthreads();
    {
        int tcx = t & 15, trx = t >> 4;
        int c0 = tcx * 8, r0 = trx * 4;
        float acc[4][8];
        #pragma unroll
        for (int j = 0; j < 4; ++j)
            #pragma unroll
            for (int q = 0; q < 8; ++q) acc[j][q] = 0.f;
        #pragma unroll 4
        for (int kk = 0; kk < 64; ++kk) {
            float4 x4 = *(const float4*)&xT[kk][r0];
            float4 wa = *(const float4*)&W1L[kk * 128 + c0];
            float4 wb = *(const float4*)&W1L[kk * 128 + c0 + 4];
            float x[4] = {x4.x, x4.y, x4.z, x4.w};
            float w[8] = {wa.x, wa.y, wa.z, wa.w, wb.x, wb.y, wb.z, wb.w};
            #pragma unroll
            for (int j = 0; j < 4; ++j)
                #pragma unroll
                for (int q = 0; q < 8; ++q)
                    acc[j][q] = fmaf(x[j], w[q], acc[j][q]);
        }
        #pragma unroll
        for (int q = 0; q < 8; ++q) {
            float bb = b1[c0 + q];
            float4 v;
            v.x = siluf(acc[0][q] + bb);
            v.y = siluf(acc[1][q] + bb);
            v.z = siluf(acc[2][q] + bb);
            v.w = siluf(acc[3][q] + bb);
            *(float4*)&hTT[c0 + q][r0] = v;
        }
    }
    __syncthreads();
    {
        int tcx = t & 7, trx = t >> 3;
        int c0 = tcx * 8, r0 = trx * 2;
        float acc[2][8];
        #pragma unroll
        for (int j = 0; j < 2; ++j)
            #pragma unroll
            for (int q = 0; q < 8; ++q) acc[j][q] = 0.f;
        #pragma unroll 4
        for (int kk = 0; kk < 128; ++kk) {
            float2 x2 = *(const float2*)&hTT[kk][r0];
            float4 wa = *(const float4*)&W2L[kk * 64 + c0];
            float4 wb = *(const float4*)&W2L[kk * 64 + c0 + 4];
            float w[8] = {wa.x, wa.y, wa.z, wa.w, wb.x, wb.y, wb.z, wb.w};
            #pragma unroll
            for (int q = 0; q < 8; ++q) {
                acc[0][q] = fmaf(x2.x, w[q], acc[0][q]);
                acc[1][q] = fmaf(x2.y, w[q], acc[1][q]);
            }
        }
        int gg = gbase + r0;
        #pragma unroll
        for (int j = 0; j < 2; ++j) {
            float o[8];
            #pragma unroll
            for (int q = 0; q < 8; ++q) o[q] = acc[j][q] + b2[c0 + q];
            *(float4*)&out[(gg + j) * 64 + c0] = make_float4(o[0], o[1], o[2], o[3]);
            *(float4*)&out[(gg + j) * 64 + c0 + 4] = make_float4(o[4], o[5], o[6], o[7]);
        }
    }
}

extern "C" void kernel_launch(void* const* d_in, const int* in_sizes, int n_in,
                              void* d_out, int out_size, void* d_ws, size_t ws_size,
                              hipStream_t stream) {
    (void)in_sizes; (void)n_in; (void)out_size; (void)ws_size;
    const float* h_flat = (const float*)d_in[0];
    const int*   z_flat = (const int*)d_in[1];
    const float* e_feat = (const float*)d_in[2];
    const int*   path_j = (const int*)d_in[3];
    const int*   path_k = (const int*)d_in[4];
    const float* r0j    = (const float*)d_in[5];
    const float* r0k    = (const float*)d_in[6];
    const float* rjk    = (const float*)d_in[7];
    const float* cosang = (const float*)d_in[8];
    const int*   pbatch = (const int*)d_in[9];
    const float* z_emb  = (const float*)d_in[11];
    const float* pe_w1  = (const float*)d_in[12];
    const float* pe_b1  = (const float*)d_in[13];
    const float* pe_w2  = (const float*)d_in[14];
    const float* pe_b2  = (const float*)d_in[15];
    const float* pe_w3  = (const float*)d_in[16];
    const float* pe_b3  = (const float*)d_in[17];
    const float* gm_w1  = (const float*)d_in[18];
    const float* gm_b1  = (const float*)d_in[19];
    const float* gm_w2  = (const float*)d_in[20];
    const float* gm_b2  = (const float*)d_in[21];
    const float* gm_w3  = (const float*)d_in[22];
    const float* gm_b3  = (const float*)d_in[23];
    const float* op_w1  = (const float*)d_in[24];
    const float* op_b1  = (const float*)d_in[25];
    const float* op_w2  = (const float*)d_in[26];
    const float* op_b2  = (const float*)d_in[27];

    float* ws  = (float*)d_ws;
    int*   wsi = (int*)d_ws;
    float* gcw = ws + GCW_OFF;
    float* agg = ws + AGG_OFF;

    hipLaunchKernelGGL(k0a, dim3(32), dim3(256), 0, stream,
                       r0j, r0k, rjk, pbatch, ws, wsi);
    hipLaunchKernelGGL(k0b, dim3(1), dim3(64), 0, stream, ws, wsi);
    hipLaunchKernelGGL(k0c, dim3(32), dim3(256), 0, stream,
                       path_j, path_k, z_flat, ws, wsi);
    hipLaunchKernelGGL(k1_tables, dim3(74), dim3(256), 0, stream,
                       z_emb, e_feat, pe_w1, pe_b1, pe_w2, pe_w3, ws);
    hipLaunchKernelGGL(k2_geom, dim3(250), dim3(256), 0, stream,
                       h_flat, r0j, r0k, rjk, cosang, path_j, path_k,
                       gm_w1, gm_b1, gm_w2, gm_b2, gm_w3, gm_b3, ws, wsi, gcw);
    hipLaunchKernelGGL(k3_pair_mfma, dim3(2660), dim3(256), 0, stream,
                       ws, wsi, gcw, agg, pe_b2, pe_b3);
    hipLaunchKernelGGL(k4_out, dim3(20), dim3(256), 0, stream,
                       ws, op_w1, op_b1, op_w2, op_b2, (float*)d_out);
}

// Round 3
// 179.019 us; speedup vs baseline: 1.4961x; 1.2525x over previous
//
#include <hip/hip_runtime.h>
#include <math.h>

typedef float f32x4 __attribute__((ext_vector_type(4)));
typedef short bf16x8 __attribute__((ext_vector_type(8)));
typedef unsigned short u16;

#define RBF_DIM 32
#define CUTOFF 5.0f
#define PI_F 3.14159265358979323846f
#define BB 16
#define PP 8000
#define NEE 80

// ws layout (f32-element offsets)
#define CW_OFF      0            // 8000
#define GCW_OFF     8000         // 8000*64
#define AGG_OFF     520000       // 16*80*64 = 81920
#define ZEJW_OFF    601920       // 101*64
#define ZEKW_OFF    608384       // 101*64
#define EFWB_OFF    614848       // 80*64
#define NORM_OFF    619968       // 16
#define AIDX_OFF    619984       // 8000 int
#define ZJA_OFF     627984       // 8000 int
#define ZKA_OFF     635984       // 8000 int
#define BOFF_OFF    643984       // 17 int
#define BCNT_OFF    644004       // 32 int
#define BSUM_OFF    644036       // 512 f32
#define BCNTB_OFF   644548       // 512 int
#define BLKOFF_OFF  645060       // 33 int
#define CHS_OFF     645096       // 266 int chunk start
#define CHC_OFF     645362       // 266 int chunk count
#define CHB_OFF     645628       // 266 int chunk batch
#define NC_OFF      645894       // 1 int
#define W2THI_OFF   645896       // 2048 f32 = 4096 u16 (W2^T hi bf16)
#define W2TLO_OFF   647944
#define W3THI_OFF   649992
#define W3TLO_OFF   652040
// end 654088 f32 (~2.62 MB)

__device__ __forceinline__ float siluf(float x) { return x / (1.f + __expf(-x)); }
__device__ __forceinline__ float cutoff_fn(float r) {
    return (r < CUTOFF) ? 0.5f * (cosf(PI_F * r / CUTOFF) + 1.f) : 0.f;
}
__device__ __forceinline__ float rbff(float r, int i) {
    r = fminf(r, CUTOFF);
    float a = r * (31.0f / CUTOFF) - (float)i;
    return __expf(-0.5f * a * a);
}
__device__ __forceinline__ u16 f2bf_rne(float x) {
    unsigned u = __float_as_uint(x);
    return (u16)((u + 0x7FFFu + ((u >> 16) & 1u)) >> 16);
}
// packed bf16 convert: dst.lo16 = bf16(a), dst.hi16 = bf16(b)
__device__ __forceinline__ unsigned cvtpk2(float a, float b) {
    unsigned r;
    asm("v_cvt_pk_bf16_f32 %0, %1, %2" : "=v"(r) : "v"(a), "v"(b));
    return r;
}
__device__ __forceinline__ void splitpack8(const float* xs, bf16x8& hi, bf16x8& lo) {
    union { bf16x8 v; unsigned u[4]; } H, L;
    #pragma unroll
    for (int d = 0; d < 4; ++d) {
        float a = xs[2 * d], b = xs[2 * d + 1];
        unsigned h = cvtpk2(a, b);
        float ra = a - __uint_as_float(h << 16);
        float rb = b - __uint_as_float(h & 0xFFFF0000u);
        H.u[d] = h;
        L.u[d] = cvtpk2(ra, rb);
    }
    hi = H.v; lo = L.v;
}

// ---------------- K0a + K1 merged: blocks 0..31 = k0a, 32..105 = k1
__global__ __launch_bounds__(256) void k0a_k1(
    const float* r0j, const float* r0k, const float* rjk, const int* pbatch,
    const float* z_emb, const float* e_feat, const float* pe_w1, const float* pe_b1,
    const float* pe_w2, const float* pe_w3,
    float* ws, int* wsi)
{
    __shared__ float cwL[256];
    __shared__ int bL[256];
    __shared__ int redC[256];
    __shared__ float embL[4 * 32];
    int blkAll = blockIdx.x, t = threadIdx.x;
    if (blkAll < 32) {
        int bi = blkAll;
        for (int i = t; i < 2560; i += 256) ws[AGG_OFF + bi*2560 + i] = 0.f;
        int p = bi*250 + t;
        float cw = 0.f; int bin = -1; int valid = 0;
        if (t < 250) {
            cw = cutoff_fn(r0j[p]) * cutoff_fn(r0k[p]) * cutoff_fn(rjk[p]);
            ws[CW_OFF + p] = cw;
            bin = pbatch[p];
            valid = (cw > 0.f) ? 1 : 0;
        }
        cwL[t] = cw; bL[t] = bin; redC[t] = valid;
        __syncthreads();
        if (t < 16) {
            float s = 0.f; int c2 = 0;
            for (int i = 0; i < 256; ++i) {
                bool m = (bL[i] == t);
                s += m ? cwL[i] : 0.f;
                c2 += (m && cwL[i] > 0.f) ? 1 : 0;
            }
            ws[BSUM_OFF + bi*16 + t] = s;
            wsi[BCNTB_OFF + bi*16 + t] = c2;
        }
        __syncthreads();
        for (int s = 128; s > 0; s >>= 1) {
            if (t < s) redC[t] += redC[t + s];
            __syncthreads();
        }
        if (t == 0) wsi[BCNT_OFF + bi] = redC[0];
        return;
    }
    int blk = blkAll - 32;
    if (blk >= 72) {
        const float* W = (blk == 72) ? pe_w2 : pe_w3;
        u16* hiD = (u16*)(ws + ((blk == 72) ? W2THI_OFF : W3THI_OFF));
        u16* loD = (u16*)(ws + ((blk == 72) ? W2TLO_OFF : W3TLO_OFF));
        for (int idx = t; idx < 4096; idx += 256) {
            int k = idx >> 6, n = idx & 63;
            float v = W[idx];
            u16 h = f2bf_rne(v);
            float hf = __uint_as_float(((unsigned)h) << 16);
            hiD[n*64 + k] = h;
            loD[n*64 + k] = f2bf_rne(v - hf);
        }
        return;
    }
    int r0, nrows, wbase;
    const float* src;
    float* dst;
    bool addb = false;
    if (blk < 26)      { r0 = blk * 4;        nrows = 101; src = z_emb;  wbase = 0;  dst = ws + ZEJW_OFF; }
    else if (blk < 52) { r0 = (blk - 26) * 4; nrows = 101; src = z_emb;  wbase = 32; dst = ws + ZEKW_OFF; }
    else               { r0 = (blk - 52) * 4; nrows = NEE; src = e_feat; wbase = 64; dst = ws + EFWB_OFF; addb = true; }
    if (t < 128) {
        int rl = t >> 5, i = t & 31;
        int r = r0 + rl;
        embL[t] = (r < nrows) ? src[r * 32 + i] : 0.f;
    }
    __syncthreads();
    int rl = t >> 6, c = t & 63;
    float acc = addb ? pe_b1[c] : 0.f;
    #pragma unroll
    for (int i = 0; i < 32; ++i)
        acc = fmaf(embL[rl * 32 + i], pe_w1[(wbase + i) * 64 + c], acc);
    int r = r0 + rl;
    if (r < nrows) dst[r * 64 + c] = acc;
}

// ---------------- K0b: scans, norm, chunk table (1 block)
__global__ __launch_bounds__(64) void k0b(float* ws, int* wsi)
{
    int t = threadIdx.x;
    if (t < 16) {
        float s = 0.f;
        for (int bi = 0; bi < 32; ++bi) s += ws[BSUM_OFF + bi*16 + t];
        ws[NORM_OFF + t] = s;
    }
    if (t == 0) {
        int off = 0;
        for (int bi = 0; bi < 32; ++bi) { wsi[BLKOFF_OFF + bi] = off; off += wsi[BCNT_OFF + bi]; }
        wsi[BLKOFF_OFF + 32] = off;
        int bs = 0;
        for (int b = 0; b < 16; ++b) {
            wsi[BOFF_OFF + b] = bs;
            int cb = 0;
            for (int bi = 0; bi < 32; ++bi) cb += wsi[BCNTB_OFF + bi*16 + b];
            bs += cb;
        }
        wsi[BOFF_OFF + 16] = bs;   // NA
        int nc = 0;
        for (int b = 0; b < 16; ++b) {
            int s0 = wsi[BOFF_OFF + b], e0 = wsi[BOFF_OFF + b + 1];
            for (int x = s0; x < e0; x += 32) {
                wsi[CHS_OFF + nc] = x;
                wsi[CHC_OFF + nc] = (e0 - x < 32) ? (e0 - x) : 32;
                wsi[CHB_OFF + nc] = b;
                nc++;
            }
        }
        wsi[NC_OFF] = nc;
    }
}

// ---------------- K0c: deterministic compaction
__global__ __launch_bounds__(256) void k0c(
    const int* pj, const int* pk, const int* zf, const float* ws, int* wsi)
{
    __shared__ int sc[256];
    int bi = blockIdx.x, t = threadIdx.x;
    int p = bi*250 + t;
    int valid = (t < 250 && ws[CW_OFF + p] > 0.f) ? 1 : 0;
    sc[t] = valid;
    __syncthreads();
    for (int off = 1; off < 256; off <<= 1) {
        int v = (t >= off) ? sc[t - off] : 0;
        __syncthreads();
        sc[t] += v;
        __syncthreads();
    }
    if (valid) {
        int pos = wsi[BLKOFF_OFF + bi] + sc[t] - 1;
        wsi[AIDX_OFF + pos] = p;
        wsi[ZJA_OFF + pos] = zf[pj[p]];
        wsi[ZKA_OFF + pos] = zf[pk[p]];
    }
}

// ---------------- K2: geom MLP (353->128->128->64), output gcw = g_geom * cw
__global__ __launch_bounds__(256) void k2_geom(
    const float* h_flat,
    const float* r0jG, const float* r0kG, const float* rjkG, const float* cosG,
    const int* pjG, const int* pkG,
    const float* W1, const float* b1, const float* W2, const float* b2,
    const float* W3, const float* b3,
    const float* ws, const int* wsi, float* gcw)
{
    __shared__ float inT[64][36];
    __shared__ float WL[64 * 128];
    __shared__ float h1T[128][36];
    __shared__ float h2T[128][36];
    __shared__ int pjL[32], pkL[32];
    __shared__ float r0jL[32], r0kL[32], rjkL[32], cosL[32], cwL[32];

    int NA = wsi[BOFF_OFF + 16];
    int apBase = blockIdx.x * 32;
    if (apBase >= NA) return;
    int t = threadIdx.x;
    if (t < 32) {
        int ap = apBase + t;
        int a = wsi[AIDX_OFF + min(ap, NA - 1)];
        pjL[t] = pjG[a]; pkL[t] = pkG[a];
        r0jL[t] = r0jG[a]; r0kL[t] = r0kG[a]; rjkL[t] = rjkG[a];
        cosL[t] = cosG[a];
        cwL[t] = ws[CW_OFF + a];
    }
    __syncthreads();

    const int tc = t & 15, tr = t >> 4;
    const int c0 = tc * 8, r0 = tr * 2;
    float acc[2][8];
    #pragma unroll
    for (int j = 0; j < 2; ++j)
        #pragma unroll
        for (int q = 0; q < 8; ++q) acc[j][q] = 0.f;

    for (int ck = 0; ck < 6; ++ck) {
        int k0 = ck * 64;
        {
            int rr = t >> 3;
            int kb = (t & 7) * 8;
            if (k0 < 256) {
                const float* hsrc = h_flat + ((k0 < 128) ? pjL[rr] : pkL[rr]) * 128
                                          + ((k0 < 128) ? k0 : (k0 - 128));
                float4 v0 = *(const float4*)(hsrc + kb);
                float4 v1 = *(const float4*)(hsrc + kb + 4);
                inT[kb + 0][rr] = v0.x; inT[kb + 1][rr] = v0.y;
                inT[kb + 2][rr] = v0.z; inT[kb + 3][rr] = v0.w;
                inT[kb + 4][rr] = v1.x; inT[kb + 5][rr] = v1.y;
                inT[kb + 6][rr] = v1.z; inT[kb + 7][rr] = v1.w;
            } else if (k0 == 256) {
                #pragma unroll
                for (int j = 0; j < 8; ++j) {
                    int kk = kb + j;
                    float r = (kk < 32) ? r0jL[rr] : r0kL[rr];
                    inT[kk][rr] = rbff(r, kk & 31);
                }
            } else {
                #pragma unroll
                for (int j = 0; j < 8; ++j) {
                    int kk = kb + j;
                    float v;
                    if (kk < 32) v = rbff(rjkL[rr], kk);
                    else if (kk == 32) v = cosL[rr];
                    else v = 0.f;
                    inT[kk][rr] = v;
                }
            }
        }
        for (int idx = t; idx < 64 * 128; idx += 256) {
            int kk = idx >> 7, c = idx & 127;
            int krow = k0 + kk;
            WL[idx] = (krow < 353) ? W1[krow * 128 + c] : 0.f;
        }
        __syncthreads();
        #pragma unroll 4
        for (int kk = 0; kk < 64; ++kk) {
            float2 in2 = *(const float2*)&inT[kk][r0];
            float4 wa = *(const float4*)&WL[kk * 128 + c0];
            float4 wb = *(const float4*)&WL[kk * 128 + c0 + 4];
            float w[8] = {wa.x, wa.y, wa.z, wa.w, wb.x, wb.y, wb.z, wb.w};
            #pragma unroll
            for (int q = 0; q < 8; ++q) {
                acc[0][q] = fmaf(in2.x, w[q], acc[0][q]);
                acc[1][q] = fmaf(in2.y, w[q], acc[1][q]);
            }
        }
        __syncthreads();
    }
    #pragma unroll
    for (int q = 0; q < 8; ++q) {
        float bb = b1[c0 + q];
        float2 v;
        v.x = siluf(acc[0][q] + bb);
        v.y = siluf(acc[1][q] + bb);
        *(float2*)&h1T[c0 + q][r0] = v;
    }
    #pragma unroll
    for (int j = 0; j < 2; ++j)
        #pragma unroll
        for (int q = 0; q < 8; ++q) acc[j][q] = 0.f;
    for (int ck = 0; ck < 2; ++ck) {
        int k0 = ck * 64;
        __syncthreads();
        for (int idx = t; idx < 64 * 128; idx += 256) {
            int kk = idx >> 7, c = idx & 127;
            WL[idx] = W2[(k0 + kk) * 128 + c];
        }
        __syncthreads();
        #pragma unroll 4
        for (int kk = 0; kk < 64; ++kk) {
            float2 in2 = *(const float2*)&h1T[k0 + kk][r0];
            float4 wa = *(const float4*)&WL[kk * 128 + c0];
            float4 wb = *(const float4*)&WL[kk * 128 + c0 + 4];
            float w[8] = {wa.x, wa.y, wa.z, wa.w, wb.x, wb.y, wb.z, wb.w};
            #pragma unroll
            for (int q = 0; q < 8; ++q) {
                acc[0][q] = fmaf(in2.x, w[q], acc[0][q]);
                acc[1][q] = fmaf(in2.y, w[q], acc[1][q]);
            }
        }
    }
    __syncthreads();
    #pragma unroll
    for (int q = 0; q < 8; ++q) {
        float bb = b2[c0 + q];
        float2 v;
        v.x = siluf(acc[0][q] + bb);
        v.y = siluf(acc[1][q] + bb);
        *(float2*)&h2T[c0 + q][r0] = v;
    }
    for (int idx = t; idx < 128 * 64; idx += 256) WL[idx] = W3[idx];
    __syncthreads();
    {
        int c3 = (t & 7) * 8;
        int r3 = t >> 3;
        float acc3[8];
        #pragma unroll
        for (int q = 0; q < 8; ++q) acc3[q] = 0.f;
        #pragma unroll 4
        for (int kk = 0; kk < 128; ++kk) {
            float in1 = h2T[kk][r3];
            float4 wa = *(const float4*)&WL[kk * 64 + c3];
            float4 wb = *(const float4*)&WL[kk * 64 + c3 + 4];
            float w[8] = {wa.x, wa.y, wa.z, wa.w, wb.x, wb.y, wb.z, wb.w};
            #pragma unroll
            for (int q = 0; q < 8; ++q) acc3[q] = fmaf(in1, w[q], acc3[q]);
        }
        int ap = apBase + r3;
        if (ap < NA) {
            float cwv = cwL[r3];
            float o[8];
            #pragma unroll
            for (int q = 0; q < 8; ++q) o[q] = (acc3[q] + b3[c3 + q]) * cwv;
            *(float4*)&gcw[ap * 64 + c3] = make_float4(o[0], o[1], o[2], o[3]);
            *(float4*)&gcw[ap * 64 + c3 + 4] = make_float4(o[4], o[5], o[6], o[7]);
        }
    }
}

// ---------------- K3: pair MLP layers 2-3 via MFMA bf16 hi/lo + contrib + aggregation
// Block = 1 chunk (<=32 paths) x 16 e-values; 4 waves; wave w -> e = et*16 + w*4 + {0..3}.
// Transposed matmul: h2^T = W2^T(A) @ h1^T(B); out3^T = W3^T(A) @ h2^T(B).
__global__ __launch_bounds__(256) void k3_pair_mfma(
    const float* ws, const int* wsi, const float* gcw, float* agg,
    const float* b2g, const float* b3g)
{
    __shared__ __align__(16) float sL[32 * 64];        // swizzled zjW+zkW sums
    __shared__ __align__(16) float gcwL[32 * 64];      // swizzled gcw tile
    __shared__ __align__(16) u16 h2buf[4][4096];       // per-wave: hi[2048] lo[2048]; reused as f32 red[64*17]

    int NC = wsi[NC_OFF];
    int bid = blockIdx.x;
    int cid = bid / 5;
    int et  = bid - cid * 5;
    if (cid >= NC) return;
    int cs  = wsi[CHS_OFF + cid];
    int cnt = wsi[CHC_OFF + cid];
    int bb  = wsi[CHB_OFF + cid];

    int t = threadIdx.x;
    int lane = t & 63, w = t >> 6;
    int c = lane & 15, g = lane >> 4;

    // stage sL (swizzled) + gcw tile (swizzled)
    {
        int p = t >> 3, kc = (t & 7) * 8;
        int ap = cs + min(p, cnt - 1);
        int zj = wsi[ZJA_OFF + ap], zk = wsi[ZKA_OFF + ap];
        const f32x4* rj = (const f32x4*)(ws + ZEJW_OFF + zj * 64 + kc);
        const f32x4* rk = (const f32x4*)(ws + ZEKW_OFF + zk * 64 + kc);
        f32x4 s0 = rj[0] + rk[0];
        f32x4 s1 = rj[1] + rk[1];
        int sw = (p & 7) << 2;
        *(f32x4*)(sL + ((p * 64 + kc) ^ sw))     = s0;
        *(f32x4*)(sL + ((p * 64 + kc + 4) ^ sw)) = s1;
        f32x4 g0 = {0.f, 0.f, 0.f, 0.f}, g1 = {0.f, 0.f, 0.f, 0.f};
        if (p < cnt) {
            g0 = *(const f32x4*)(gcw + (cs + p) * 64 + kc);
            g1 = *(const f32x4*)(gcw + (cs + p) * 64 + kc + 4);
        }
        *(f32x4*)(gcwL + ((p * 64 + kc) ^ sw))     = g0;
        *(f32x4*)(gcwL + ((p * 64 + kc + 4) ^ sw)) = g1;
    }

    // W fragments (resident), biases
    const u16* w2hi = (const u16*)(ws + W2THI_OFF);
    const u16* w2lo = (const u16*)(ws + W2TLO_OFF);
    const u16* w3hi = (const u16*)(ws + W3THI_OFF);
    const u16* w3lo = (const u16*)(ws + W3TLO_OFF);
    bf16x8 A2h[4][2], A2l[4][2], A3h[4][2], A3l[4][2];
    #pragma unroll
    for (int mt = 0; mt < 4; ++mt)
        #pragma unroll
        for (int ks = 0; ks < 2; ++ks) {
            int off = (mt * 16 + c) * 64 + ks * 32 + g * 8;
            A2h[mt][ks] = *(const bf16x8*)(w2hi + off);
            A2l[mt][ks] = *(const bf16x8*)(w2lo + off);
            A3h[mt][ks] = *(const bf16x8*)(w3hi + off);
            A3l[mt][ks] = *(const bf16x8*)(w3lo + off);
        }
    f32x4 b2f[4], b3f[4];
    #pragma unroll
    for (int mt = 0; mt < 4; ++mt) {
        b2f[mt] = *(const f32x4*)(b2g + mt * 16 + 4 * g);
        b3f[mt] = *(const f32x4*)(b3g + mt * 16 + 4 * g);
    }
    __syncthreads();   // sL + gcwL ready

    u16* myh = h2buf[w];
    u16* myl = h2buf[w] + 2048;
    float* red = (float*)h2buf[w];
    const float* efp = ws + EFWB_OFF;

    #pragma unroll 1
    for (int ei = 0; ei < 4; ++ei) {
        int e = et * 16 + w * 4 + ei;
        // h1 B-fragments: h1 = silu(sL + ef[e])
        bf16x8 Bh[2][2], Bl[2][2];
        #pragma unroll
        for (int ks = 0; ks < 2; ++ks) {
            f32x4 e0 = *(const f32x4*)(efp + e * 64 + ks * 32 + g * 8);
            f32x4 e1 = *(const f32x4*)(efp + e * 64 + ks * 32 + g * 8 + 4);
            #pragma unroll
            for (int nt = 0; nt < 2; ++nt) {
                int p = nt * 16 + c;
                int sw = (p & 7) << 2;
                int base = p * 64 + ks * 32 + g * 8;
                f32x4 x0 = *(const f32x4*)(sL + (base ^ sw));
                f32x4 x1 = *(const f32x4*)(sL + ((base + 4) ^ sw));
                x0 += e0; x1 += e1;
                float xs[8];
                #pragma unroll
                for (int i = 0; i < 4; ++i) { xs[i] = siluf(x0[i]); xs[4 + i] = siluf(x1[i]); }
                splitpack8(xs, Bh[nt][ks], Bl[nt][ks]);
            }
        }
        // layer 2 MFMA (3-pass hi/lo)
        f32x4 acc[4][2];
        #pragma unroll
        for (int mt = 0; mt < 4; ++mt)
            #pragma unroll
            for (int nt = 0; nt < 2; ++nt) {
                f32x4 d = {0.f, 0.f, 0.f, 0.f};
                #pragma unroll
                for (int ks = 0; ks < 2; ++ks) {
                    d = __builtin_amdgcn_mfma_f32_16x16x32_bf16(A2h[mt][ks], Bh[nt][ks], d, 0, 0, 0);
                    d = __builtin_amdgcn_mfma_f32_16x16x32_bf16(A2h[mt][ks], Bl[nt][ks], d, 0, 0, 0);
                    d = __builtin_amdgcn_mfma_f32_16x16x32_bf16(A2l[mt][ks], Bh[nt][ks], d, 0, 0, 0);
                }
                acc[mt][nt] = d;
            }
        // h2 = silu(acc + b2) -> per-wave LDS planes (bf16 hi/lo), XOR-swizzled
        #pragma unroll
        for (int mt = 0; mt < 4; ++mt)
            #pragma unroll
            for (int nt = 0; nt < 2; ++nt) {
                f32x4 h = acc[mt][nt] + b2f[mt];
                float v0 = siluf(h[0]), v1 = siluf(h[1]), v2 = siluf(h[2]), v3 = siluf(h[3]);
                unsigned h01 = cvtpk2(v0, v1), h23 = cvtpk2(v2, v3);
                float l0 = v0 - __uint_as_float(h01 << 16);
                float l1 = v1 - __uint_as_float(h01 & 0xFFFF0000u);
                float l2 = v2 - __uint_as_float(h23 << 16);
                float l3 = v3 - __uint_as_float(h23 & 0xFFFF0000u);
                unsigned lo01 = cvtpk2(l0, l1), lo23 = cvtpk2(l2, l3);
                int p = nt * 16 + c;
                int idx = (p * 64 + mt * 16 + 4 * g) ^ ((p & 7) << 3);
                uint2 uh, ul;
                uh.x = h01; uh.y = h23;
                ul.x = lo01; ul.y = lo23;
                *(uint2*)(myh + idx) = uh;
                *(uint2*)(myl + idx) = ul;
            }
        // layer 3 B-fragments from LDS (in-wave dep; compiler inserts lgkmcnt)
        bf16x8 Ch[2][2], Cl[2][2];
        #pragma unroll
        for (int nt = 0; nt < 2; ++nt)
            #pragma unroll
            for (int ks = 0; ks < 2; ++ks) {
                int p = nt * 16 + c;
                int idx = (p * 64 + ks * 32 + g * 8) ^ ((p & 7) << 3);
                Ch[nt][ks] = *(const bf16x8*)(myh + idx);
                Cl[nt][ks] = *(const bf16x8*)(myl + idx);
            }
        // layer 3 MFMA
        #pragma unroll
        for (int mt = 0; mt < 4; ++mt)
            #pragma unroll
            for (int nt = 0; nt < 2; ++nt) {
                f32x4 d = {0.f, 0.f, 0.f, 0.f};
                #pragma unroll
                for (int ks = 0; ks < 2; ++ks) {
                    d = __builtin_amdgcn_mfma_f32_16x16x32_bf16(A3h[mt][ks], Ch[nt][ks], d, 0, 0, 0);
                    d = __builtin_amdgcn_mfma_f32_16x16x32_bf16(A3h[mt][ks], Cl[nt][ks], d, 0, 0, 0);
                    d = __builtin_amdgcn_mfma_f32_16x16x32_bf16(A3l[mt][ks], Ch[nt][ks], d, 0, 0, 0);
                }
                acc[mt][nt] = d;
            }
        // epilogue: contrib = (out3 + b3) * gcw (from LDS), in-lane nt-sum,
        // per-wave LDS transpose-reduce over the 16 c-lanes, 1 atomic/lane
        float part[16];
        #pragma unroll
        for (int i = 0; i < 16; ++i) part[i] = 0.f;
        #pragma unroll
        for (int mt = 0; mt < 4; ++mt)
            #pragma unroll
            for (int nt = 0; nt < 2; ++nt) {
                f32x4 o = acc[mt][nt] + b3f[mt];
                int pl = nt * 16 + c;
                int gidx = (pl * 64 + mt * 16 + 4 * g) ^ ((pl & 7) << 2);
                f32x4 gv = *(const f32x4*)(gcwL + gidx);
                #pragma unroll
                for (int r = 0; r < 4; ++r) part[mt * 4 + r] += o[r] * gv[r];
            }
        // red[f][c], f = mt*16 + g*4 + r, row stride 17 (conflict-free)
        #pragma unroll
        for (int i = 0; i < 16; ++i) {
            int mt = i >> 2, r = i & 3;
            red[(mt * 16 + g * 4 + r) * 17 + c] = part[i];
        }
        float s = 0.f;
        #pragma unroll
        for (int i = 0; i < 16; ++i) s += red[lane * 17 + i];
        atomicAdd(agg + (bb * NEE + e) * 64 + lane, s);
    }
}

// ---------------- K4: normalize + out MLP (64->128->64)
__global__ __launch_bounds__(256) void k4_out(
    const float* ws, const float* W1, const float* b1,
    const float* W2, const float* b2, float* out)
{
    __shared__ float xT[64][68];
    __shared__ float W1L[64 * 128];
    __shared__ float hTT[128][68];
    __shared__ float W2L[128 * 64];
    __shared__ float normL[16];
    int t = threadIdx.x;
    int gbase = blockIdx.x * 64;
    if (t < 16) normL[t] = 1.f / fmaxf(ws[NORM_OFF + t], 1e-8f);
    for (int idx = t; idx < 8192; idx += 256) { W1L[idx] = W1[idx]; W2L[idx] = W2[idx]; }
    __syncthreads();
    {
        int r = t & 63, cq = t >> 6;
        int gg = gbase + r;
        int b = gg / NEE;
        float rn = normL[b];
        const float* arow = ws + AGG_OFF + gg * 64 + cq * 16;
        #pragma unroll
        for (int q = 0; q < 4; ++q) {
            float4 v = *(const float4*)(arow + q * 4);
            int c = cq * 16 + q * 4;
            xT[c + 0][r] = v.x * rn; xT[c + 1][r] = v.y * rn;
            xT[c + 2][r] = v.z * rn; xT[c + 3][r] = v.w * rn;
        }
    }
    __syncthreads();
    {
        int tcx = t & 15, trx = t >> 4;
        int c0 = tcx * 8, r0 = trx * 4;
        float acc[4][8];
        #pragma unroll
        for (int j = 0; j < 4; ++j)
            #pragma unroll
            for (int q = 0; q < 8; ++q) acc[j][q] = 0.f;
        #pragma unroll 4
        for (int kk = 0; kk < 64; ++kk) {
            float4 x4 = *(const float4*)&xT[kk][r0];
            float4 wa = *(const float4*)&W1L[kk * 128 + c0];
            float4 wb = *(const float4*)&W1L[kk * 128 + c0 + 4];
            float x[4] = {x4.x, x4.y, x4.z, x4.w};
            float w[8] = {wa.x, wa.y, wa.z, wa.w, wb.x, wb.y, wb.z, wb.w};
            #pragma unroll
            for (int j = 0; j < 4; ++j)
                #pragma unroll
                for (int q = 0; q < 8; ++q)
                    acc[j][q] = fmaf(x[j], w[q], acc[j][q]);
        }
        #pragma unroll
        for (int q = 0; q < 8; ++q) {
            float bb = b1[c0 + q];
            float4 v;
            v.x = siluf(acc[0][q] + bb);
            v.y = siluf(acc[1][q] + bb);
            v.z = siluf(acc[2][q] + bb);
            v.w = siluf(acc[3][q] + bb);
            *(float4*)&hTT[c0 + q][r0] = v;
        }
    }
    __syncthreads();
    {
        int tcx = t & 7, trx = t >> 3;
        int c0 = tcx * 8, r0 = trx * 2;
        float acc[2][8];
        #pragma unroll
        for (int j = 0; j < 2; ++j)
            #pragma unroll
            for (int q = 0; q < 8; ++q) acc[j][q] = 0.f;
        #pragma unroll 4
        for (int kk = 0; kk < 128; ++kk) {
            float2 x2 = *(const float2*)&hTT[kk][r0];
            float4 wa = *(const float4*)&W2L[kk * 64 + c0];
            float4 wb = *(const float4*)&W2L[kk * 64 + c0 + 4];
            float w[8] = {wa.x, wa.y, wa.z, wa.w, wb.x, wb.y, wb.z, wb.w};
            #pragma unroll
            for (int q = 0; q < 8; ++q) {
                acc[0][q] = fmaf(x2.x, w[q], acc[0][q]);
                acc[1][q] = fmaf(x2.y, w[q], acc[1][q]);
            }
        }
        int gg = gbase + r0;
        #pragma unroll
        for (int j = 0; j < 2; ++j) {
            float o[8];
            #pragma unroll
            for (int q = 0; q < 8; ++q) o[q] = acc[j][q] + b2[c0 + q];
            *(float4*)&out[(gg + j) * 64 + c0] = make_float4(o[0], o[1], o[2], o[3]);
            *(float4*)&out[(gg + j) * 64 + c0 + 4] = make_float4(o[4], o[5], o[6], o[7]);
        }
    }
}

extern "C" void kernel_launch(void* const* d_in, const int* in_sizes, int n_in,
                              void* d_out, int out_size, void* d_ws, size_t ws_size,
                              hipStream_t stream) {
    (void)in_sizes; (void)n_in; (void)out_size; (void)ws_size;
    const float* h_flat = (const float*)d_in[0];
    const int*   z_flat = (const int*)d_in[1];
    const float* e_feat = (const float*)d_in[2];
    const int*   path_j = (const int*)d_in[3];
    const int*   path_k = (const int*)d_in[4];
    const float* r0j    = (const float*)d_in[5];
    const float* r0k    = (const float*)d_in[6];
    const float* rjk    = (const float*)d_in[7];
    const float* cosang = (const float*)d_in[8];
    const int*   pbatch = (const int*)d_in[9];
    const float* z_emb  = (const float*)d_in[11];
    const float* pe_w1  = (const float*)d_in[12];
    const float* pe_b1  = (const float*)d_in[13];
    const float* pe_w2  = (const float*)d_in[14];
    const float* pe_b2  = (const float*)d_in[15];
    const float* pe_w3  = (const float*)d_in[16];
    const float* pe_b3  = (const float*)d_in[17];
    const float* gm_w1  = (const float*)d_in[18];
    const float* gm_b1  = (const float*)d_in[19];
    const float* gm_w2  = (const float*)d_in[20];
    const float* gm_b2  = (const float*)d_in[21];
    const float* gm_w3  = (const float*)d_in[22];
    const float* gm_b3  = (const float*)d_in[23];
    const float* op_w1  = (const float*)d_in[24];
    const float* op_b1  = (const float*)d_in[25];
    const float* op_w2  = (const float*)d_in[26];
    const float* op_b2  = (const float*)d_in[27];

    float* ws  = (float*)d_ws;
    int*   wsi = (int*)d_ws;
    float* gcw = ws + GCW_OFF;
    float* agg = ws + AGG_OFF;

    hipLaunchKernelGGL(k0a_k1, dim3(106), dim3(256), 0, stream,
                       r0j, r0k, rjk, pbatch,
                       z_emb, e_feat, pe_w1, pe_b1, pe_w2, pe_w3, ws, wsi);
    hipLaunchKernelGGL(k0b, dim3(1), dim3(64), 0, stream, ws, wsi);
    hipLaunchKernelGGL(k0c, dim3(32), dim3(256), 0, stream,
                       path_j, path_k, z_flat, ws, wsi);
    hipLaunchKernelGGL(k2_geom, dim3(250), dim3(256), 0, stream,
                       h_flat, r0j, r0k, rjk, cosang, path_j, path_k,
                       gm_w1, gm_b1, gm_w2, gm_b2, gm_w3, gm_b3, ws, wsi, gcw);
    hipLaunchKernelGGL(k3_pair_mfma, dim3(1330), dim3(256), 0, stream,
                       ws, wsi, gcw, agg, pe_b2, pe_b3);
    hipLaunchKernelGGL(k4_out, dim3(20), dim3(256), 0, stream,
                       ws, op_w1, op_b1, op_w2, op_b2, (float*)d_out);
}

// Round 4
// 148.299 us; speedup vs baseline: 1.8060x; 1.2071x over previous
//
#include <hip/hip_runtime.h>
#include <math.h>

typedef float f32x4 __attribute__((ext_vector_type(4)));
typedef short bf16x8 __attribute__((ext_vector_type(8)));
typedef unsigned short u16;

#define RBF_DIM 32
#define CUTOFF 5.0f
#define PI_F 3.14159265358979323846f
#define BB 16
#define PP 8000
#define NEE 80

// ws layout (f32-element offsets)
#define CW_OFF      0            // 8000
#define GCW_OFF     8000         // 8000*64
#define AGG_OFF     520000       // 16*80*64 = 81920
#define ZEJW_OFF    601920       // 101*64
#define ZEKW_OFF    608384       // 101*64
#define EFWB_OFF    614848       // 80*64
#define NORM_OFF    619968       // 16
#define AIDX_OFF    619984       // 8000 int
#define ZJA_OFF     627984       // 8000 int
#define ZKA_OFF     635984       // 8000 int
#define BOFF_OFF    643984       // 17 int
#define BCNT_OFF    644004       // 32 int
#define BSUM_OFF    644036       // 512 f32
#define BCNTB_OFF   644548       // 512 int
#define BLKOFF_OFF  645060       // 33 int
#define CHS_OFF     645096       // 266 int chunk start
#define CHC_OFF     645362       // 266 int chunk count
#define CHB_OFF     645628       // 266 int chunk batch
#define NC_OFF      645894       // 1 int
#define W2THI_OFF   645896       // 4096 u16 (pair W2^T hi)
#define W2TLO_OFF   647944
#define W3THI_OFF   649992
#define W3TLO_OFF   652040
// new for MFMA geom path:
#define PJA_OFF     654088       // 8000 int (compacted path_j)
#define PKA_OFF     662088       // 8000 int
#define CWA_OFF     670088       // 8000 f32 (compacted cw)
#define HHI_OFF     678088       // u16[1024*128] h_flat hi
#define HLO_OFF     743624       // u16[1024*128]
#define GW1JKH_OFF  809160       // u16[256*128]  [hjW;hkW] A-plane hi
#define GW1JKL_OFF  825544
#define GW1RH_OFF   841928       // u16[128*128]  W1rbf^T hi (k 97 pad 128)
#define GW1RL_OFF   850120
#define GW2H_OFF    858312       // u16[128*128]  gm_W2^T hi
#define GW2L_OFF    866504
#define GW3H_OFF    874696       // u16[64*128]   gm_W3^T hi
#define GW3L_OFF    878792
#define HJW_OFF     882888       // f32[1024*128]
#define HKW_OFF     1013960      // f32[1024*128]
// end 1145032 f32 (~4.6 MB)

__device__ __forceinline__ float siluf(float x) { return x / (1.f + __expf(-x)); }
__device__ __forceinline__ float cutoff_fn(float r) {
    return (r < CUTOFF) ? 0.5f * (cosf(PI_F * r / CUTOFF) + 1.f) : 0.f;
}
__device__ __forceinline__ float rbff(float r, int i) {
    r = fminf(r, CUTOFF);
    float a = r * (31.0f / CUTOFF) - (float)i;
    return __expf(-0.5f * a * a);
}
__device__ __forceinline__ u16 f2bf_rne(float x) {
    unsigned u = __float_as_uint(x);
    return (u16)((u + 0x7FFFu + ((u >> 16) & 1u)) >> 16);
}
__device__ __forceinline__ unsigned cvtpk2(float a, float b) {
    unsigned r;
    asm("v_cvt_pk_bf16_f32 %0, %1, %2" : "=v"(r) : "v"(a), "v"(b));
    return r;
}
__device__ __forceinline__ void splitpack8(const float* xs, bf16x8& hi, bf16x8& lo) {
    union { bf16x8 v; unsigned u[4]; } H, L;
    #pragma unroll
    for (int d = 0; d < 4; ++d) {
        float a = xs[2 * d], b = xs[2 * d + 1];
        unsigned h = cvtpk2(a, b);
        float ra = a - __uint_as_float(h << 16);
        float rb = b - __uint_as_float(h & 0xFFFF0000u);
        H.u[d] = h;
        L.u[d] = cvtpk2(ra, rb);
    }
    hi = H.v; lo = L.v;
}

// ---------------- K0a+K1+weight-splits merged (grid 143)
// blk 0..31: cw/agg-zero/counts; 32..103: pair layer-1 tables; 104/105: pair W2T/W3T;
// 106..137: h_flat bf16 split; 138/139: gm_w1jk^T; 140: gm_w1rbf^T; 141: gm_w2^T; 142: gm_w3^T
__global__ __launch_bounds__(256) void k0a_k1(
    const float* r0j, const float* r0k, const float* rjk, const int* pbatch,
    const float* z_emb, const float* e_feat, const float* pe_w1, const float* pe_b1,
    const float* pe_w2, const float* pe_w3,
    const float* h_flat, const float* gm_w1, const float* gm_w2, const float* gm_w3,
    float* ws, int* wsi)
{
    __shared__ float cwL[256];
    __shared__ int bL[256];
    __shared__ int redC[256];
    __shared__ float embL[4 * 32];
    int blkAll = blockIdx.x, t = threadIdx.x;
    if (blkAll < 32) {
        int bi = blkAll;
        for (int i = t; i < 2560; i += 256) ws[AGG_OFF + bi*2560 + i] = 0.f;
        int p = bi*250 + t;
        float cw = 0.f; int bin = -1; int valid = 0;
        if (t < 250) {
            cw = cutoff_fn(r0j[p]) * cutoff_fn(r0k[p]) * cutoff_fn(rjk[p]);
            ws[CW_OFF + p] = cw;
            bin = pbatch[p];
            valid = (cw > 0.f) ? 1 : 0;
        }
        cwL[t] = cw; bL[t] = bin; redC[t] = valid;
        __syncthreads();
        if (t < 16) {
            float s = 0.f; int c2 = 0;
            for (int i = 0; i < 256; ++i) {
                bool m = (bL[i] == t);
                s += m ? cwL[i] : 0.f;
                c2 += (m && cwL[i] > 0.f) ? 1 : 0;
            }
            ws[BSUM_OFF + bi*16 + t] = s;
            wsi[BCNTB_OFF + bi*16 + t] = c2;
        }
        __syncthreads();
        for (int s = 128; s > 0; s >>= 1) {
            if (t < s) redC[t] += redC[t + s];
            __syncthreads();
        }
        if (t == 0) wsi[BCNT_OFF + bi] = redC[0];
        return;
    }
    if (blkAll >= 106) {
        int blk = blkAll - 106;
        if (blk < 32) {            // h_flat split
            u16* hh = (u16*)(ws + HHI_OFF);
            u16* hl = (u16*)(ws + HLO_OFF);
            int base = blk * 4096;
            for (int idx = t; idx < 4096; idx += 256) {
                int e = base + idx;
                float v = h_flat[e];
                u16 h = f2bf_rne(v);
                hh[e] = h;
                hl[e] = f2bf_rne(v - __uint_as_float(((unsigned)h) << 16));
            }
        } else if (blk < 34) {     // gm_w1jk^T (256x128)
            u16* wh = (u16*)(ws + GW1JKH_OFF);
            u16* wl = (u16*)(ws + GW1JKL_OFF);
            int base = (blk - 32) * 16384;
            for (int idx = t; idx < 16384; idx += 256) {
                int e = base + idx;
                int m = e >> 7, k = e & 127;
                float v = gm_w1[((m < 128) ? k : (128 + k)) * 128 + (m & 127)];
                u16 h = f2bf_rne(v);
                wh[e] = h;
                wl[e] = f2bf_rne(v - __uint_as_float(((unsigned)h) << 16));
            }
        } else if (blk == 34) {    // gm_w1rbf^T (128x128, k<97)
            u16* wh = (u16*)(ws + GW1RH_OFF);
            u16* wl = (u16*)(ws + GW1RL_OFF);
            for (int e = t; e < 16384; e += 256) {
                int m = e >> 7, k = e & 127;
                float v = (k < 97) ? gm_w1[(256 + k) * 128 + m] : 0.f;
                u16 h = f2bf_rne(v);
                wh[e] = h;
                wl[e] = f2bf_rne(v - __uint_as_float(((unsigned)h) << 16));
            }
        } else if (blk == 35) {    // gm_w2^T
            u16* wh = (u16*)(ws + GW2H_OFF);
            u16* wl = (u16*)(ws + GW2L_OFF);
            for (int e = t; e < 16384; e += 256) {
                int m = e >> 7, k = e & 127;
                float v = gm_w2[k * 128 + m];
                u16 h = f2bf_rne(v);
                wh[e] = h;
                wl[e] = f2bf_rne(v - __uint_as_float(((unsigned)h) << 16));
            }
        } else {                   // gm_w3^T (64x128)
            u16* wh = (u16*)(ws + GW3H_OFF);
            u16* wl = (u16*)(ws + GW3L_OFF);
            for (int e = t; e < 8192; e += 256) {
                int m = e >> 7, k = e & 127;
                float v = gm_w3[k * 64 + m];
                u16 h = f2bf_rne(v);
                wh[e] = h;
                wl[e] = f2bf_rne(v - __uint_as_float(((unsigned)h) << 16));
            }
        }
        return;
    }
    int blk = blkAll - 32;
    if (blk >= 72) {
        const float* W = (blk == 72) ? pe_w2 : pe_w3;
        u16* hiD = (u16*)(ws + ((blk == 72) ? W2THI_OFF : W3THI_OFF));
        u16* loD = (u16*)(ws + ((blk == 72) ? W2TLO_OFF : W3TLO_OFF));
        for (int idx = t; idx < 4096; idx += 256) {
            int k = idx >> 6, n = idx & 63;
            float v = W[idx];
            u16 h = f2bf_rne(v);
            float hf = __uint_as_float(((unsigned)h) << 16);
            hiD[n*64 + k] = h;
            loD[n*64 + k] = f2bf_rne(v - hf);
        }
        return;
    }
    int r0, nrows, wbase;
    const float* src;
    float* dst;
    bool addb = false;
    if (blk < 26)      { r0 = blk * 4;        nrows = 101; src = z_emb;  wbase = 0;  dst = ws + ZEJW_OFF; }
    else if (blk < 52) { r0 = (blk - 26) * 4; nrows = 101; src = z_emb;  wbase = 32; dst = ws + ZEKW_OFF; }
    else               { r0 = (blk - 52) * 4; nrows = NEE; src = e_feat; wbase = 64; dst = ws + EFWB_OFF; addb = true; }
    if (t < 128) {
        int rl = t >> 5, i = t & 31;
        int r = r0 + rl;
        embL[t] = (r < nrows) ? src[r * 32 + i] : 0.f;
    }
    __syncthreads();
    int rl = t >> 6, c = t & 63;
    float acc = addb ? pe_b1[c] : 0.f;
    #pragma unroll
    for (int i = 0; i < 32; ++i)
        acc = fmaf(embL[rl * 32 + i], pe_w1[(wbase + i) * 64 + c], acc);
    int r = r0 + rl;
    if (r < nrows) dst[r * 64 + c] = acc;
}

// ---------------- K0b: scans, norm, chunk table (1 block)
__global__ __launch_bounds__(64) void k0b(float* ws, int* wsi)
{
    int t = threadIdx.x;
    if (t < 16) {
        float s = 0.f;
        for (int bi = 0; bi < 32; ++bi) s += ws[BSUM_OFF + bi*16 + t];
        ws[NORM_OFF + t] = s;
    }
    if (t == 0) {
        int off = 0;
        for (int bi = 0; bi < 32; ++bi) { wsi[BLKOFF_OFF + bi] = off; off += wsi[BCNT_OFF + bi]; }
        wsi[BLKOFF_OFF + 32] = off;
        int bs = 0;
        for (int b = 0; b < 16; ++b) {
            wsi[BOFF_OFF + b] = bs;
            int cb = 0;
            for (int bi = 0; bi < 32; ++bi) cb += wsi[BCNTB_OFF + bi*16 + b];
            bs += cb;
        }
        wsi[BOFF_OFF + 16] = bs;   // NA
        int nc = 0;
        for (int b = 0; b < 16; ++b) {
            int s0 = wsi[BOFF_OFF + b], e0 = wsi[BOFF_OFF + b + 1];
            for (int x = s0; x < e0; x += 32) {
                wsi[CHS_OFF + nc] = x;
                wsi[CHC_OFF + nc] = (e0 - x < 32) ? (e0 - x) : 32;
                wsi[CHB_OFF + nc] = b;
                nc++;
            }
        }
        wsi[NC_OFF] = nc;
    }
}

// ---------------- K0c: deterministic compaction (+ pj/pk/cw compaction)
__global__ __launch_bounds__(256) void k0c(
    const int* pj, const int* pk, const int* zf, float* ws, int* wsi)
{
    __shared__ int sc[256];
    int bi = blockIdx.x, t = threadIdx.x;
    int p = bi*250 + t;
    int valid = (t < 250 && ws[CW_OFF + p] > 0.f) ? 1 : 0;
    sc[t] = valid;
    __syncthreads();
    for (int off = 1; off < 256; off <<= 1) {
        int v = (t >= off) ? sc[t - off] : 0;
        __syncthreads();
        sc[t] += v;
        __syncthreads();
    }
    if (valid) {
        int pos = wsi[BLKOFF_OFF + bi] + sc[t] - 1;
        int pjv = pj[p], pkv = pk[p];
        wsi[AIDX_OFF + pos] = p;
        wsi[ZJA_OFF + pos] = zf[pjv];
        wsi[ZKA_OFF + pos] = zf[pkv];
        wsi[PJA_OFF + pos] = pjv;
        wsi[PKA_OFF + pos] = pkv;
        ws[CWA_OFF + pos] = ws[CW_OFF + p];
    }
}

// ---------------- K1b: hjW/hkW for all atoms: [hjW;hkW](256 x 1024) = W1jk^T @ h^T
__global__ __launch_bounds__(256) void k1b_hw(float* ws)
{
    int t = threadIdx.x;
    int a0 = blockIdx.x * 64;
    int lane = t & 63, w = t >> 6, c = lane & 15, g = lane >> 4;
    const u16* hh = (const u16*)(ws + HHI_OFF);
    const u16* hl = (const u16*)(ws + HLO_OFF);
    const u16* wh = (const u16*)(ws + GW1JKH_OFF);
    const u16* wl = (const u16*)(ws + GW1JKL_OFF);
    f32x4 acc[4][4];
    #pragma unroll
    for (int i = 0; i < 4; ++i)
        #pragma unroll
        for (int j = 0; j < 4; ++j) acc[i][j] = (f32x4){0.f, 0.f, 0.f, 0.f};
    #pragma unroll 1
    for (int ks = 0; ks < 4; ++ks) {
        bf16x8 Ah[4], Al[4], Bh[4], Bl[4];
        #pragma unroll
        for (int mt = 0; mt < 4; ++mt) {
            int off = (w * 64 + mt * 16 + c) * 128 + ks * 32 + g * 8;
            Ah[mt] = *(const bf16x8*)(wh + off);
            Al[mt] = *(const bf16x8*)(wl + off);
        }
        #pragma unroll
        for (int nt = 0; nt < 4; ++nt) {
            int off = (a0 + nt * 16 + c) * 128 + ks * 32 + g * 8;
            Bh[nt] = *(const bf16x8*)(hh + off);
            Bl[nt] = *(const bf16x8*)(hl + off);
        }
        #pragma unroll
        for (int mt = 0; mt < 4; ++mt)
            #pragma unroll
            for (int nt = 0; nt < 4; ++nt) {
                f32x4 d = acc[mt][nt];
                d = __builtin_amdgcn_mfma_f32_16x16x32_bf16(Ah[mt], Bh[nt], d, 0, 0, 0);
                d = __builtin_amdgcn_mfma_f32_16x16x32_bf16(Ah[mt], Bl[nt], d, 0, 0, 0);
                d = __builtin_amdgcn_mfma_f32_16x16x32_bf16(Al[mt], Bh[nt], d, 0, 0, 0);
                acc[mt][nt] = d;
            }
    }
    float* dst = ws + ((w < 2) ? HJW_OFF : HKW_OFF);
    #pragma unroll
    for (int mt = 0; mt < 4; ++mt)
        #pragma unroll
        for (int nt = 0; nt < 4; ++nt) {
            int m = (w & 1) * 64 + mt * 16 + g * 4;
            int a = a0 + nt * 16 + c;
            *(f32x4*)(dst + a * 128 + m) = acc[mt][nt];
        }
}

// ---------------- K2: geom MLP via MFMA. Per block: one 32-path chunk.
// L1: h1^T(128xP) = W1rbf^T @ rbf^T + sum3 + b1 (silu); L2: 128; L3: 64 -> gcw
__global__ __launch_bounds__(256) void k2_geom_mfma(
    const float* r0jG, const float* r0kG, const float* rjkG, const float* cosG,
    const float* b1g, const float* b2g, const float* b3g,
    float* ws, const int* wsi, float* gcw)
{
    __shared__ __align__(16) float sum3L[32 * 128];
    __shared__ __align__(16) u16 rbfH[4096], rbfL[4096];
    __shared__ __align__(16) u16 h1H[4096], h1L[4096];
    __shared__ __align__(16) u16 h2H[4096], h2L[4096];
    __shared__ int pjS[32], pkS[32];
    __shared__ float cwS[32], r0jS[32], r0kS[32], rjkS[32], cosS[32];

    int NC = wsi[NC_OFF];
    int cid = blockIdx.x;
    if (cid >= NC) return;
    int cs = wsi[CHS_OFF + cid], cnt = wsi[CHC_OFF + cid];
    int t = threadIdx.x, lane = t & 63, w = t >> 6, c = lane & 15, g = lane >> 4;

    if (t < 32) {
        int ap = cs + min(t, cnt - 1);
        int a = wsi[AIDX_OFF + ap];
        pjS[t] = wsi[PJA_OFF + ap]; pkS[t] = wsi[PKA_OFF + ap];
        cwS[t] = ws[CWA_OFF + ap];
        r0jS[t] = r0jG[a]; r0kS[t] = r0kG[a]; rjkS[t] = rjkG[a]; cosS[t] = cosG[a];
    }
    __syncthreads();
    // sum3 = hjW[pj] + hkW[pk]  (swizzled f32)
    {
        int p = t >> 3, kc = (t & 7) * 16;
        const float* rj = ws + HJW_OFF + pjS[p] * 128 + kc;
        const float* rk = ws + HKW_OFF + pkS[p] * 128 + kc;
        #pragma unroll
        for (int q = 0; q < 4; ++q) {
            f32x4 v = *(const f32x4*)(rj + q * 4) + *(const f32x4*)(rk + q * 4);
            *(f32x4*)(sum3L + ((p * 128 + kc + q * 4) ^ ((p & 7) << 2))) = v;
        }
    }
    // rbf input planes (bf16 hi/lo, swizzled)
    {
        int p = t >> 3, k0 = (t & 7) * 16;
        float r0jv = r0jS[p], r0kv = r0kS[p], rjkv = rjkS[p], cv = cosS[p];
        #pragma unroll
        for (int hf = 0; hf < 2; ++hf) {
            int kb = k0 + hf * 8;
            float xs[8];
            #pragma unroll
            for (int i = 0; i < 8; ++i) {
                int k = kb + i;
                float v;
                if (k < 32) v = rbff(r0jv, k);
                else if (k < 64) v = rbff(r0kv, k - 32);
                else if (k < 96) v = rbff(rjkv, k - 64);
                else if (k == 96) v = cv;
                else v = 0.f;
                xs[i] = v;
            }
            bf16x8 hi, lo;
            splitpack8(xs, hi, lo);
            int idx = (p * 128 + kb) ^ ((p & 7) << 3);
            *(bf16x8*)(rbfH + idx) = hi;
            *(bf16x8*)(rbfL + idx) = lo;
        }
    }
    __syncthreads();

    const u16* w1h = (const u16*)(ws + GW1RH_OFF);
    const u16* w1l = (const u16*)(ws + GW1RL_OFF);
    const u16* w2h = (const u16*)(ws + GW2H_OFF);
    const u16* w2l = (const u16*)(ws + GW2L_OFF);
    const u16* w3h = (const u16*)(ws + GW3H_OFF);
    const u16* w3l = (const u16*)(ws + GW3L_OFF);

    // ---- L1 (M=128: wave w owns mt {2w, 2w+1}; N=32: nt 0..1)
    f32x4 acc[2][2];
    #pragma unroll
    for (int i = 0; i < 2; ++i)
        #pragma unroll
        for (int j = 0; j < 2; ++j) acc[i][j] = (f32x4){0.f, 0.f, 0.f, 0.f};
    #pragma unroll 1
    for (int ks = 0; ks < 4; ++ks) {
        bf16x8 Ah[2], Al[2], Bh[2], Bl[2];
        #pragma unroll
        for (int ml = 0; ml < 2; ++ml) {
            int off = ((w * 2 + ml) * 16 + c) * 128 + ks * 32 + g * 8;
            Ah[ml] = *(const bf16x8*)(w1h + off);
            Al[ml] = *(const bf16x8*)(w1l + off);
        }
        #pragma unroll
        for (int nt = 0; nt < 2; ++nt) {
            int p = nt * 16 + c;
            int idx = (p * 128 + ks * 32 + g * 8) ^ ((p & 7) << 3);
            Bh[nt] = *(const bf16x8*)(rbfH + idx);
            Bl[nt] = *(const bf16x8*)(rbfL + idx);
        }
        #pragma unroll
        for (int ml = 0; ml < 2; ++ml)
            #pragma unroll
            for (int nt = 0; nt < 2; ++nt) {
                f32x4 d = acc[ml][nt];
                d = __builtin_amdgcn_mfma_f32_16x16x32_bf16(Ah[ml], Bh[nt], d, 0, 0, 0);
                d = __builtin_amdgcn_mfma_f32_16x16x32_bf16(Ah[ml], Bl[nt], d, 0, 0, 0);
                d = __builtin_amdgcn_mfma_f32_16x16x32_bf16(Al[ml], Bh[nt], d, 0, 0, 0);
                acc[ml][nt] = d;
            }
    }
    // epilogue L1: h1 = silu(acc + sum3 + b1) -> h1 planes
    #pragma unroll
    for (int ml = 0; ml < 2; ++ml)
        #pragma unroll
        for (int nt = 0; nt < 2; ++nt) {
            int p = nt * 16 + c;
            int m0 = (w * 2 + ml) * 16 + g * 4;
            f32x4 s = *(const f32x4*)(sum3L + ((p * 128 + m0) ^ ((p & 7) << 2)));
            f32x4 bb = *(const f32x4*)(b1g + m0);
            f32x4 x = acc[ml][nt] + s + bb;
            float v0 = siluf(x[0]), v1 = siluf(x[1]), v2 = siluf(x[2]), v3 = siluf(x[3]);
            unsigned h01 = cvtpk2(v0, v1), h23 = cvtpk2(v2, v3);
            float l0 = v0 - __uint_as_float(h01 << 16);
            float l1 = v1 - __uint_as_float(h01 & 0xFFFF0000u);
            float l2 = v2 - __uint_as_float(h23 << 16);
            float l3 = v3 - __uint_as_float(h23 & 0xFFFF0000u);
            unsigned lo01 = cvtpk2(l0, l1), lo23 = cvtpk2(l2, l3);
            int idx = (p * 128 + m0) ^ ((p & 7) << 3);
            uint2 uh; uh.x = h01; uh.y = h23;
            uint2 ul; ul.x = lo01; ul.y = lo23;
            *(uint2*)(h1H + idx) = uh;
            *(uint2*)(h1L + idx) = ul;
        }
    __syncthreads();

    // ---- L2 (M=128, K=128)
    #pragma unroll
    for (int i = 0; i < 2; ++i)
        #pragma unroll
        for (int j = 0; j < 2; ++j) acc[i][j] = (f32x4){0.f, 0.f, 0.f, 0.f};
    #pragma unroll 1
    for (int ks = 0; ks < 4; ++ks) {
        bf16x8 Ah[2], Al[2], Bh[2], Bl[2];
        #pragma unroll
        for (int ml = 0; ml < 2; ++ml) {
            int off = ((w * 2 + ml) * 16 + c) * 128 + ks * 32 + g * 8;
            Ah[ml] = *(const bf16x8*)(w2h + off);
            Al[ml] = *(const bf16x8*)(w2l + off);
        }
        #pragma unroll
        for (int nt = 0; nt < 2; ++nt) {
            int p = nt * 16 + c;
            int idx = (p * 128 + ks * 32 + g * 8) ^ ((p & 7) << 3);
            Bh[nt] = *(const bf16x8*)(h1H + idx);
            Bl[nt] = *(const bf16x8*)(h1L + idx);
        }
        #pragma unroll
        for (int ml = 0; ml < 2; ++ml)
            #pragma unroll
            for (int nt = 0; nt < 2; ++nt) {
                f32x4 d = acc[ml][nt];
                d = __builtin_amdgcn_mfma_f32_16x16x32_bf16(Ah[ml], Bh[nt], d, 0, 0, 0);
                d = __builtin_amdgcn_mfma_f32_16x16x32_bf16(Ah[ml], Bl[nt], d, 0, 0, 0);
                d = __builtin_amdgcn_mfma_f32_16x16x32_bf16(Al[ml], Bh[nt], d, 0, 0, 0);
                acc[ml][nt] = d;
            }
    }
    #pragma unroll
    for (int ml = 0; ml < 2; ++ml)
        #pragma unroll
        for (int nt = 0; nt < 2; ++nt) {
            int p = nt * 16 + c;
            int m0 = (w * 2 + ml) * 16 + g * 4;
            f32x4 bb = *(const f32x4*)(b2g + m0);
            f32x4 x = acc[ml][nt] + bb;
            float v0 = siluf(x[0]), v1 = siluf(x[1]), v2 = siluf(x[2]), v3 = siluf(x[3]);
            unsigned h01 = cvtpk2(v0, v1), h23 = cvtpk2(v2, v3);
            float l0 = v0 - __uint_as_float(h01 << 16);
            float l1 = v1 - __uint_as_float(h01 & 0xFFFF0000u);
            float l2 = v2 - __uint_as_float(h23 << 16);
            float l3 = v3 - __uint_as_float(h23 & 0xFFFF0000u);
            unsigned lo01 = cvtpk2(l0, l1), lo23 = cvtpk2(l2, l3);
            int idx = (p * 128 + m0) ^ ((p & 7) << 3);
            uint2 uh; uh.x = h01; uh.y = h23;
            uint2 ul; ul.x = lo01; ul.y = lo23;
            *(uint2*)(h2H + idx) = uh;
            *(uint2*)(h2L + idx) = ul;
        }
    __syncthreads();

    // ---- L3 (M=64: wave w owns mt=w; K=128) -> gcw
    f32x4 acc3[2];
    acc3[0] = (f32x4){0.f, 0.f, 0.f, 0.f};
    acc3[1] = (f32x4){0.f, 0.f, 0.f, 0.f};
    #pragma unroll 1
    for (int ks = 0; ks < 4; ++ks) {
        bf16x8 Ah, Al, Bh[2], Bl[2];
        {
            int off = (w * 16 + c) * 128 + ks * 32 + g * 8;
            Ah = *(const bf16x8*)(w3h + off);
            Al = *(const bf16x8*)(w3l + off);
        }
        #pragma unroll
        for (int nt = 0; nt < 2; ++nt) {
            int p = nt * 16 + c;
            int idx = (p * 128 + ks * 32 + g * 8) ^ ((p & 7) << 3);
            Bh[nt] = *(const bf16x8*)(h2H + idx);
            Bl[nt] = *(const bf16x8*)(h2L + idx);
        }
        #pragma unroll
        for (int nt = 0; nt < 2; ++nt) {
            f32x4 d = acc3[nt];
            d = __builtin_amdgcn_mfma_f32_16x16x32_bf16(Ah, Bh[nt], d, 0, 0, 0);
            d = __builtin_amdgcn_mfma_f32_16x16x32_bf16(Ah, Bl[nt], d, 0, 0, 0);
            d = __builtin_amdgcn_mfma_f32_16x16x32_bf16(Al, Bh[nt], d, 0, 0, 0);
            acc3[nt] = d;
        }
    }
    {
        int m0 = w * 16 + g * 4;
        f32x4 bb = *(const f32x4*)(b3g + m0);
        #pragma unroll
        for (int nt = 0; nt < 2; ++nt) {
            int p = nt * 16 + c;
            if (p < cnt) {
                f32x4 o = (acc3[nt] + bb) * cwS[p];
                *(f32x4*)(gcw + (cs + p) * 64 + m0) = o;
            }
        }
    }
}

// ---------------- K3: pair MLP layers 2-3 via MFMA bf16 hi/lo + contrib + aggregation
__global__ __launch_bounds__(256) void k3_pair_mfma(
    const float* ws, const int* wsi, const float* gcw, float* agg,
    const float* b2g, const float* b3g)
{
    __shared__ __align__(16) float sL[32 * 64];
    __shared__ __align__(16) float gcwL[32 * 64];
    __shared__ __align__(16) u16 h2buf[4][4096];

    int NC = wsi[NC_OFF];
    int bid = blockIdx.x;
    int cid = bid / 5;
    int et  = bid - cid * 5;
    if (cid >= NC) return;
    int cs  = wsi[CHS_OFF + cid];
    int cnt = wsi[CHC_OFF + cid];
    int bb  = wsi[CHB_OFF + cid];

    int t = threadIdx.x;
    int lane = t & 63, w = t >> 6;
    int c = lane & 15, g = lane >> 4;

    {
        int p = t >> 3, kc = (t & 7) * 8;
        int ap = cs + min(p, cnt - 1);
        int zj = wsi[ZJA_OFF + ap], zk = wsi[ZKA_OFF + ap];
        const f32x4* rj = (const f32x4*)(ws + ZEJW_OFF + zj * 64 + kc);
        const f32x4* rk = (const f32x4*)(ws + ZEKW_OFF + zk * 64 + kc);
        f32x4 s0 = rj[0] + rk[0];
        f32x4 s1 = rj[1] + rk[1];
        int sw = (p & 7) << 2;
        *(f32x4*)(sL + ((p * 64 + kc) ^ sw))     = s0;
        *(f32x4*)(sL + ((p * 64 + kc + 4) ^ sw)) = s1;
        f32x4 g0 = {0.f, 0.f, 0.f, 0.f}, g1 = {0.f, 0.f, 0.f, 0.f};
        if (p < cnt) {
            g0 = *(const f32x4*)(gcw + (cs + p) * 64 + kc);
            g1 = *(const f32x4*)(gcw + (cs + p) * 64 + kc + 4);
        }
        *(f32x4*)(gcwL + ((p * 64 + kc) ^ sw))     = g0;
        *(f32x4*)(gcwL + ((p * 64 + kc + 4) ^ sw)) = g1;
    }

    const u16* w2hi = (const u16*)(ws + W2THI_OFF);
    const u16* w2lo = (const u16*)(ws + W2TLO_OFF);
    const u16* w3hi = (const u16*)(ws + W3THI_OFF);
    const u16* w3lo = (const u16*)(ws + W3TLO_OFF);
    bf16x8 A2h[4][2], A2l[4][2], A3h[4][2], A3l[4][2];
    #pragma unroll
    for (int mt = 0; mt < 4; ++mt)
        #pragma unroll
        for (int ks = 0; ks < 2; ++ks) {
            int off = (mt * 16 + c) * 64 + ks * 32 + g * 8;
            A2h[mt][ks] = *(const bf16x8*)(w2hi + off);
            A2l[mt][ks] = *(const bf16x8*)(w2lo + off);
            A3h[mt][ks] = *(const bf16x8*)(w3hi + off);
            A3l[mt][ks] = *(const bf16x8*)(w3lo + off);
        }
    f32x4 b2f[4], b3f[4];
    #pragma unroll
    for (int mt = 0; mt < 4; ++mt) {
        b2f[mt] = *(const f32x4*)(b2g + mt * 16 + 4 * g);
        b3f[mt] = *(const f32x4*)(b3g + mt * 16 + 4 * g);
    }
    __syncthreads();

    u16* myh = h2buf[w];
    u16* myl = h2buf[w] + 2048;
    float* red = (float*)h2buf[w];
    const float* efp = ws + EFWB_OFF;

    #pragma unroll 1
    for (int ei = 0; ei < 4; ++ei) {
        int e = et * 16 + w * 4 + ei;
        bf16x8 Bh[2][2], Bl[2][2];
        #pragma unroll
        for (int ks = 0; ks < 2; ++ks) {
            f32x4 e0 = *(const f32x4*)(efp + e * 64 + ks * 32 + g * 8);
            f32x4 e1 = *(const f32x4*)(efp + e * 64 + ks * 32 + g * 8 + 4);
            #pragma unroll
            for (int nt = 0; nt < 2; ++nt) {
                int p = nt * 16 + c;
                int sw = (p & 7) << 2;
                int base = p * 64 + ks * 32 + g * 8;
                f32x4 x0 = *(const f32x4*)(sL + (base ^ sw));
                f32x4 x1 = *(const f32x4*)(sL + ((base + 4) ^ sw));
                x0 += e0; x1 += e1;
                float xs[8];
                #pragma unroll
                for (int i = 0; i < 4; ++i) { xs[i] = siluf(x0[i]); xs[4 + i] = siluf(x1[i]); }
                splitpack8(xs, Bh[nt][ks], Bl[nt][ks]);
            }
        }
        f32x4 acc[4][2];
        #pragma unroll
        for (int mt = 0; mt < 4; ++mt)
            #pragma unroll
            for (int nt = 0; nt < 2; ++nt) {
                f32x4 d = {0.f, 0.f, 0.f, 0.f};
                #pragma unroll
                for (int ks = 0; ks < 2; ++ks) {
                    d = __builtin_amdgcn_mfma_f32_16x16x32_bf16(A2h[mt][ks], Bh[nt][ks], d, 0, 0, 0);
                    d = __builtin_amdgcn_mfma_f32_16x16x32_bf16(A2h[mt][ks], Bl[nt][ks], d, 0, 0, 0);
                    d = __builtin_amdgcn_mfma_f32_16x16x32_bf16(A2l[mt][ks], Bh[nt][ks], d, 0, 0, 0);
                }
                acc[mt][nt] = d;
            }
        #pragma unroll
        for (int mt = 0; mt < 4; ++mt)
            #pragma unroll
            for (int nt = 0; nt < 2; ++nt) {
                f32x4 h = acc[mt][nt] + b2f[mt];
                float v0 = siluf(h[0]), v1 = siluf(h[1]), v2 = siluf(h[2]), v3 = siluf(h[3]);
                unsigned h01 = cvtpk2(v0, v1), h23 = cvtpk2(v2, v3);
                float l0 = v0 - __uint_as_float(h01 << 16);
                float l1 = v1 - __uint_as_float(h01 & 0xFFFF0000u);
                float l2 = v2 - __uint_as_float(h23 << 16);
                float l3 = v3 - __uint_as_float(h23 & 0xFFFF0000u);
                unsigned lo01 = cvtpk2(l0, l1), lo23 = cvtpk2(l2, l3);
                int p = nt * 16 + c;
                int idx = (p * 64 + mt * 16 + 4 * g) ^ ((p & 7) << 3);
                uint2 uh, ul;
                uh.x = h01; uh.y = h23;
                ul.x = lo01; ul.y = lo23;
                *(uint2*)(myh + idx) = uh;
                *(uint2*)(myl + idx) = ul;
            }
        bf16x8 Ch[2][2], Cl[2][2];
        #pragma unroll
        for (int nt = 0; nt < 2; ++nt)
            #pragma unroll
            for (int ks = 0; ks < 2; ++ks) {
                int p = nt * 16 + c;
                int idx = (p * 64 + ks * 32 + g * 8) ^ ((p & 7) << 3);
                Ch[nt][ks] = *(const bf16x8*)(myh + idx);
                Cl[nt][ks] = *(const bf16x8*)(myl + idx);
            }
        #pragma unroll
        for (int mt = 0; mt < 4; ++mt)
            #pragma unroll
            for (int nt = 0; nt < 2; ++nt) {
                f32x4 d = {0.f, 0.f, 0.f, 0.f};
                #pragma unroll
                for (int ks = 0; ks < 2; ++ks) {
                    d = __builtin_amdgcn_mfma_f32_16x16x32_bf16(A3h[mt][ks], Ch[nt][ks], d, 0, 0, 0);
                    d = __builtin_amdgcn_mfma_f32_16x16x32_bf16(A3h[mt][ks], Cl[nt][ks], d, 0, 0, 0);
                    d = __builtin_amdgcn_mfma_f32_16x16x32_bf16(A3l[mt][ks], Ch[nt][ks], d, 0, 0, 0);
                }
                acc[mt][nt] = d;
            }
        float part[16];
        #pragma unroll
        for (int i = 0; i < 16; ++i) part[i] = 0.f;
        #pragma unroll
        for (int mt = 0; mt < 4; ++mt)
            #pragma unroll
            for (int nt = 0; nt < 2; ++nt) {
                f32x4 o = acc[mt][nt] + b3f[mt];
                int pl = nt * 16 + c;
                int gidx = (pl * 64 + mt * 16 + 4 * g) ^ ((pl & 7) << 2);
                f32x4 gv = *(const f32x4*)(gcwL + gidx);
                #pragma unroll
                for (int r = 0; r < 4; ++r) part[mt * 4 + r] += o[r] * gv[r];
            }
        #pragma unroll
        for (int i = 0; i < 16; ++i) {
            int mt = i >> 2, r = i & 3;
            red[(mt * 16 + g * 4 + r) * 17 + c] = part[i];
        }
        float s = 0.f;
        #pragma unroll
        for (int i = 0; i < 16; ++i) s += red[lane * 17 + i];
        atomicAdd(agg + (bb * NEE + e) * 64 + lane, s);
    }
}

// ---------------- K4: normalize + out MLP (64->128->64)
__global__ __launch_bounds__(256) void k4_out(
    const float* ws, const float* W1, const float* b1,
    const float* W2, const float* b2, float* out)
{
    __shared__ float xT[64][68];
    __shared__ float W1L[64 * 128];
    __shared__ float hTT[128][68];
    __shared__ float W2L[128 * 64];
    __shared__ float normL[16];
    int t = threadIdx.x;
    int gbase = blockIdx.x * 64;
    if (t < 16) normL[t] = 1.f / fmaxf(ws[NORM_OFF + t], 1e-8f);
    for (int idx = t; idx < 8192; idx += 256) { W1L[idx] = W1[idx]; W2L[idx] = W2[idx]; }
    __syncthreads();
    {
        int r = t & 63, cq = t >> 6;
        int gg = gbase + r;
        int b = gg / NEE;
        float rn = normL[b];
        const float* arow = ws + AGG_OFF + gg * 64 + cq * 16;
        #pragma unroll
        for (int q = 0; q < 4; ++q) {
            float4 v = *(const float4*)(arow + q * 4);
            int c = cq * 16 + q * 4;
            xT[c + 0][r] = v.x * rn; xT[c + 1][r] = v.y * rn;
            xT[c + 2][r] = v.z * rn; xT[c + 3][r] = v.w * rn;
        }
    }
    __syncthreads();
    {
        int tcx = t & 15, trx = t >> 4;
        int c0 = tcx * 8, r0 = trx * 4;
        float acc[4][8];
        #pragma unroll
        for (int j = 0; j < 4; ++j)
            #pragma unroll
            for (int q = 0; q < 8; ++q) acc[j][q] = 0.f;
        #pragma unroll 4
        for (int kk = 0; kk < 64; ++kk) {
            float4 x4 = *(const float4*)&xT[kk][r0];
            float4 wa = *(const float4*)&W1L[kk * 128 + c0];
            float4 wb = *(const float4*)&W1L[kk * 128 + c0 + 4];
            float x[4] = {x4.x, x4.y, x4.z, x4.w};
            float w[8] = {wa.x, wa.y, wa.z, wa.w, wb.x, wb.y, wb.z, wb.w};
            #pragma unroll
            for (int j = 0; j < 4; ++j)
                #pragma unroll
                for (int q = 0; q < 8; ++q)
                    acc[j][q] = fmaf(x[j], w[q], acc[j][q]);
        }
        #pragma unroll
        for (int q = 0; q < 8; ++q) {
            float bb = b1[c0 + q];
            float4 v;
            v.x = siluf(acc[0][q] + bb);
            v.y = siluf(acc[1][q] + bb);
            v.z = siluf(acc[2][q] + bb);
            v.w = siluf(acc[3][q] + bb);
            *(float4*)&hTT[c0 + q][r0] = v;
        }
    }
    __syncthreads();
    {
        int tcx = t & 7, trx = t >> 3;
        int c0 = tcx * 8, r0 = trx * 2;
        float acc[2][8];
        #pragma unroll
        for (int j = 0; j < 2; ++j)
            #pragma unroll
            for (int q = 0; q < 8; ++q) acc[j][q] = 0.f;
        #pragma unroll 4
        for (int kk = 0; kk < 128; ++kk) {
            float2 x2 = *(const float2*)&hTT[kk][r0];
            float4 wa = *(const float4*)&W2L[kk * 64 + c0];
            float4 wb = *(const float4*)&W2L[kk * 64 + c0 + 4];
            float w[8] = {wa.x, wa.y, wa.z, wa.w, wb.x, wb.y, wb.z, wb.w};
            #pragma unroll
            for (int q = 0; q < 8; ++q) {
                acc[0][q] = fmaf(x2.x, w[q], acc[0][q]);
                acc[1][q] = fmaf(x2.y, w[q], acc[1][q]);
            }
        }
        int gg = gbase + r0;
        #pragma unroll
        for (int j = 0; j < 2; ++j) {
            float o[8];
            #pragma unroll
            for (int q = 0; q < 8; ++q) o[q] = acc[j][q] + b2[c0 + q];
            *(float4*)&out[(gg + j) * 64 + c0] = make_float4(o[0], o[1], o[2], o[3]);
            *(float4*)&out[(gg + j) * 64 + c0 + 4] = make_float4(o[4], o[5], o[6], o[7]);
        }
    }
}

extern "C" void kernel_launch(void* const* d_in, const int* in_sizes, int n_in,
                              void* d_out, int out_size, void* d_ws, size_t ws_size,
                              hipStream_t stream) {
    (void)in_sizes; (void)n_in; (void)out_size; (void)ws_size;
    const float* h_flat = (const float*)d_in[0];
    const int*   z_flat = (const int*)d_in[1];
    const float* e_feat = (const float*)d_in[2];
    const int*   path_j = (const int*)d_in[3];
    const int*   path_k = (const int*)d_in[4];
    const float* r0j    = (const float*)d_in[5];
    const float* r0k    = (const float*)d_in[6];
    const float* rjk    = (const float*)d_in[7];
    const float* cosang = (const float*)d_in[8];
    const int*   pbatch = (const int*)d_in[9];
    const float* z_emb  = (const float*)d_in[11];
    const float* pe_w1  = (const float*)d_in[12];
    const float* pe_b1  = (const float*)d_in[13];
    const float* pe_w2  = (const float*)d_in[14];
    const float* pe_b2  = (const float*)d_in[15];
    const float* pe_w3  = (const float*)d_in[16];
    const float* pe_b3  = (const float*)d_in[17];
    const float* gm_w1  = (const float*)d_in[18];
    const float* gm_b1  = (const float*)d_in[19];
    const float* gm_w2  = (const float*)d_in[20];
    const float* gm_b2  = (const float*)d_in[21];
    const float* gm_w3  = (const float*)d_in[22];
    const float* gm_b3  = (const float*)d_in[23];
    const float* op_w1  = (const float*)d_in[24];
    const float* op_b1  = (const float*)d_in[25];
    const float* op_w2  = (const float*)d_in[26];
    const float* op_b2  = (const float*)d_in[27];

    float* ws  = (float*)d_ws;
    int*   wsi = (int*)d_ws;
    float* gcw = ws + GCW_OFF;
    float* agg = ws + AGG_OFF;

    hipLaunchKernelGGL(k0a_k1, dim3(143), dim3(256), 0, stream,
                       r0j, r0k, rjk, pbatch,
                       z_emb, e_feat, pe_w1, pe_b1, pe_w2, pe_w3,
                       h_flat, gm_w1, gm_w2, gm_w3, ws, wsi);
    hipLaunchKernelGGL(k0b, dim3(1), dim3(64), 0, stream, ws, wsi);
    hipLaunchKernelGGL(k0c, dim3(32), dim3(256), 0, stream,
                       path_j, path_k, z_flat, ws, wsi);
    hipLaunchKernelGGL(k1b_hw, dim3(16), dim3(256), 0, stream, ws);
    hipLaunchKernelGGL(k2_geom_mfma, dim3(266), dim3(256), 0, stream,
                       r0j, r0k, rjk, cosang,
                       gm_b1, gm_b2, gm_b3, ws, wsi, gcw);
    hipLaunchKernelGGL(k3_pair_mfma, dim3(1330), dim3(256), 0, stream,
                       ws, wsi, gcw, agg, pe_b2, pe_b3);
    hipLaunchKernelGGL(k4_out, dim3(20), dim3(256), 0, stream,
                       ws, op_w1, op_b1, op_w2, op_b2, (float*)d_out);
}